// Round 2
// 207.211 us; speedup vs baseline: 1.0889x; 1.0889x over previous
//
#include <hip/hip_runtime.h>
#include <math.h>

// B=4, H=16, S=2048, D=64 causal attention. fp32 in, fp32 out.
// R8: R7 structure with the two unverified numerics changes reverted (bisect).
//  KEPT (structural, paper-verified):
//  - fa_prep: K -> bf16 [head][kv][d], chunk ^= kv&7 (T2); V -> bf16 transposed
//    tile-major [head][tile][d][64kv], chunk ^= d&7. O(S) conversion, once.
//  - fa_fwd: K/V tiles staged via global_load_lds (zero staging VALU, linear
//    copy), double-buffered LDS, swizzled reads are bank-even.
//  - log2-domain scores (LOG2E folded into Q scale; 2^(x*log2e) == e^x exact).
//  REVERTED vs R7 (suspect set for the 0.34 absmax failure):
//  - defer-max rescale -> unconditional R6-style rescale each tile.
//  - v_cvt_pk_bf16_f32 -> pack_bf16 bit-trick (R6-proven) for P.
//  Fallback to R6 kernel if ws_size < 32 MiB.

#define S_LEN 2048
#define D_DIM 64
#define TK 64
#define NHEAD 64
#define MNEG -30000.0f
#define LSTR 72          // fallback kernel only
#define PREP_KBLK 4096

typedef __attribute__((ext_vector_type(8))) short bf16x8;
typedef __attribute__((ext_vector_type(4))) float f32x4;

static __device__ __forceinline__ float fast_exp2(float x) {
#if __has_builtin(__builtin_amdgcn_exp2f)
    return __builtin_amdgcn_exp2f(x);   // v_exp_f32: 2^x, large-negative -> 0
#else
    float r;
    asm volatile("v_exp_f32 %0, %1\n\ts_nop 1" : "=v"(r) : "v"(x));
    return r;
#endif
}

// round-half-up fp32->bf16 pair, packed into one dword (a=low, b=high)
static __device__ __forceinline__ unsigned int pack_bf16(float a, float b) {
    union { float f; unsigned int u; } ca, cb;
    ca.f = a; cb.f = b;
    unsigned int ua = ca.u + 0x8000u;
    unsigned int ub = cb.u + 0x8000u;
    return (ua >> 16) | (ub & 0xFFFF0000u);
}

typedef const __attribute__((address_space(1))) unsigned int* gas1_t;
typedef __attribute__((address_space(3))) unsigned int* las3_t;
// async global->LDS, 16B per lane. LDS dest is wave-uniform base (+lane*16 in HW).
static __device__ __forceinline__ void stage16(const void* g, void* l) {
    __builtin_amdgcn_global_load_lds((gas1_t)g, (las3_t)l, 16, 0, 0);
}

// ---------------------------------------------------------------------------
// Prep: K -> kb (bf16, row-chunk-swizzled), V -> vb (bf16, transposed,
// tile-major, row-chunk-swizzled). Blocks [0,PREP_KBLK): K. Rest: V.
// ---------------------------------------------------------------------------
__global__ __launch_bounds__(256)
void fa_prep(const float* __restrict__ kg, const float* __restrict__ vg,
             unsigned short* __restrict__ kb, unsigned short* __restrict__ vb)
{
    const int tid = threadIdx.x;
    const int bid = blockIdx.x;
    if (bid < PREP_KBLK) {
        // one 16B chunk (8 d-elems) of one K row per thread
        const int cid = bid * 256 + tid;          // (head*S + kv)*8 + ch
        const int ch  = cid & 7;
        const int row = cid >> 3;                 // head*S + kv
        const int kv  = row & (S_LEN - 1);
        const float4* s = reinterpret_cast<const float4*>(kg + (size_t)row * D_DIM + ch * 8);
        float4 a = s[0], b = s[1];
        uint4 w;
        w.x = pack_bf16(a.x, a.y); w.y = pack_bf16(a.z, a.w);
        w.z = pack_bf16(b.x, b.y); w.w = pack_bf16(b.z, b.w);
        const int dst = ch ^ (kv & 7);            // T2 swizzle
        *reinterpret_cast<uint4*>(kb + (size_t)row * D_DIM + dst * 8) = w;
    } else {
        // one 64x64 V tile per wave; lane = (kv-group kg8, d-group dg)
        const int wv   = (bid - PREP_KBLK) * 4 + (tid >> 6);  // head*32 + t
        const int lane = tid & 63;
        const int kg8  = lane >> 3;
        const int dg   = lane & 7;
        const float* s = vg + ((size_t)wv * TK + kg8 * 8) * D_DIM + dg * 8;
        float va[8][8];                            // [kv in group][d in group]
        #pragma unroll
        for (int i = 0; i < 8; ++i) {
            const float4* sp = reinterpret_cast<const float4*>(s + (size_t)i * D_DIM);
            float4 x = sp[0], y = sp[1];
            va[i][0] = x.x; va[i][1] = x.y; va[i][2] = x.z; va[i][3] = x.w;
            va[i][4] = y.x; va[i][5] = y.y; va[i][6] = y.z; va[i][7] = y.w;
        }
        unsigned short* db = vb + (size_t)wv * (TK * D_DIM);  // tile base (8 KB)
        #pragma unroll
        for (int j = 0; j < 8; ++j) {
            const int d = dg * 8 + j;             // d&7 == j
            uint4 w;
            w.x = pack_bf16(va[0][j], va[1][j]);
            w.y = pack_bf16(va[2][j], va[3][j]);
            w.z = pack_bf16(va[4][j], va[5][j]);
            w.w = pack_bf16(va[6][j], va[7][j]);
            *reinterpret_cast<uint4*>(db + d * D_DIM + 8 * (kg8 ^ j)) = w;
        }
    }
}

// ---------------------------------------------------------------------------
// Main: flash fwd, S^T formulation, bf16 K/V from workspace.
// LDS = 2*8K (K dbuf) + 2*8K (V dbuf) + 8K (P) = 40960 B -> 4 blocks/CU.
// ---------------------------------------------------------------------------
__global__ __launch_bounds__(256, 4)
void fa_fwd(const float* __restrict__ qg,
            const unsigned short* __restrict__ kb,
            const unsigned short* __restrict__ vb,
            float* __restrict__ og)
{
    const int head = blockIdx.x;          // fast dim -> XCD spread
    const int pr   = blockIdx.y;          // 0..15: q-tiles {pr, 31-pr}
    const int tid  = threadIdx.x;
    const int wave = tid >> 6;
    const int lane = tid & 63;
    const int m16  = lane & 15;
    const int quad = lane >> 4;

    __shared__ unsigned short Kl[2][TK * D_DIM];   // swizzled [kv][d] bf16
    __shared__ unsigned short Vt[2][TK * D_DIM];   // swizzled [d][kv] bf16
    __shared__ unsigned short Pl[4][16 * TK];      // per-wave swizzled [q][kv]

    const size_t hoff = (size_t)head * S_LEN * D_DIM;
    const unsigned short* kbh = kb + hoff;
    const unsigned short* vbh = vb + hoff;
    float* __restrict__ ogh = og + hoff;

    // swizzled byte columns within a 128B row (row&7 == m16&7 for all rows used)
    const int swz  = (m16 & 7) << 4;
    const int colA = (quad * 16) ^ swz;
    const int colB = (64 + quad * 16) ^ swz;
    const int rowB = m16 * 128;
    const int sgo  = wave * 512 + lane * 8;   // staging src offset (shorts)

    char* klds = (char*)&Kl[0][0];
    char* vlds = (char*)&Vt[0][0];
    char* plds = (char*)&Pl[0][0] + wave * 2048 + m16 * 128;
    char* kw   = klds + wave * 1024;          // wave-uniform stage dest (buf 0)
    char* vw   = vlds + wave * 1024;

    const float QSC = 0.18033688011112042f;   // 1/8 * log2(e): scores in log2 domain

    for (int pass = 0; pass < 2; ++pass) {
        const int q0 = ((pass == 0) ? pr : (31 - pr)) * TK;
        const int T  = q0 >> 6;               // last (diagonal) tile index

        // ---- Q fragment (B operand): n=q=m16, k=d=quad*8+j; scaled 1/8*log2e
        bf16x8 qf[2];
        {
            const float* qp = qg + hoff + (size_t)(q0 + wave * 16 + m16) * D_DIM + quad * 8;
            #pragma unroll
            for (int c = 0; c < 2; ++c) {
                float4 a = reinterpret_cast<const float4*>(qp + c * 32)[0];
                float4 b = reinterpret_cast<const float4*>(qp + c * 32)[1];
                unsigned int u0 = pack_bf16(a.x * QSC, a.y * QSC);
                unsigned int u1 = pack_bf16(a.z * QSC, a.w * QSC);
                unsigned int u2 = pack_bf16(b.x * QSC, b.y * QSC);
                unsigned int u3 = pack_bf16(b.z * QSC, b.w * QSC);
                qf[c][0] = (short)(u0 & 0xFFFF); qf[c][1] = (short)(u0 >> 16);
                qf[c][2] = (short)(u1 & 0xFFFF); qf[c][3] = (short)(u1 >> 16);
                qf[c][4] = (short)(u2 & 0xFFFF); qf[c][5] = (short)(u2 >> 16);
                qf[c][6] = (short)(u3 & 0xFFFF); qf[c][7] = (short)(u3 >> 16);
            }
        }

        float m_i = MNEG, l_i = 0.f;
        f32x4 oacc[4];
        #pragma unroll
        for (int nc = 0; nc < 4; ++nc) oacc[nc] = (f32x4){0.f, 0.f, 0.f, 0.f};

        // ---- prologue: stage tile 0 into buf 0 (4x global_load_lds / wave)
        {
            const unsigned short* ks = kbh + sgo;
            const unsigned short* vs = vbh + sgo;
            stage16(ks,        kw);
            stage16(ks + 2048, kw + 4096);
            stage16(vs,        vw);
            stage16(vs + 2048, vw + 4096);
        }
        __syncthreads();   // compiler drains vmcnt(0) before s_barrier

        int cur = 0;
        for (int t = 0; t <= T; ++t) {
            // ---- issue next-tile stage first: HBM/L2 latency hides under compute
            if (t < T) {
                const unsigned short* ks = kbh + (size_t)(t + 1) * 4096 + sgo;
                const unsigned short* vs = vbh + (size_t)(t + 1) * 4096 + sgo;
                const int nb = (cur ^ 1) * 8192;
                stage16(ks,        kw + nb);
                stage16(ks + 2048, kw + nb + 4096);
                stage16(vs,        vw + nb);
                stage16(vs + 2048, vw + nb + 4096);
            }

            const char* kt = klds + cur * 8192;
            const char* vt = vlds + cur * 8192;

            // ---- S^T = K·Q^T  (C: row=kv=nt*16+quad*4+r, col=q=m16), log2 domain
            float sv[4][4];
            #pragma unroll
            for (int nt = 0; nt < 4; ++nt) {
                f32x4 acc = (f32x4){0.f, 0.f, 0.f, 0.f};
                const char* kr = kt + nt * 2048 + rowB;
                bf16x8 kf0 = *reinterpret_cast<const bf16x8*>(kr + colA);
                bf16x8 kf1 = *reinterpret_cast<const bf16x8*>(kr + colB);
                acc = __builtin_amdgcn_mfma_f32_16x16x32_bf16(kf0, qf[0], acc, 0, 0, 0);
                acc = __builtin_amdgcn_mfma_f32_16x16x32_bf16(kf1, qf[1], acc, 0, 0, 0);
                #pragma unroll
                for (int r = 0; r < 4; ++r) sv[nt][r] = acc[r];
            }

            // ---- causal mask (diagonal tile only)
            if (t == T) {
                #pragma unroll
                for (int nt = 0; nt < 4; ++nt)
                    #pragma unroll
                    for (int r = 0; r < 4; ++r)
                        if (nt * 16 + quad * 4 + r > wave * 16 + m16) sv[nt][r] = MNEG;
            }

            // ---- online softmax (log2 domain), unconditional rescale (R6-style)
            float a0 = fmaxf(fmaxf(sv[0][0], sv[0][1]), fmaxf(sv[0][2], sv[0][3]));
            float a1 = fmaxf(fmaxf(sv[1][0], sv[1][1]), fmaxf(sv[1][2], sv[1][3]));
            float a2 = fmaxf(fmaxf(sv[2][0], sv[2][1]), fmaxf(sv[2][2], sv[2][3]));
            float a3 = fmaxf(fmaxf(sv[3][0], sv[3][1]), fmaxf(sv[3][2], sv[3][3]));
            float rm = fmaxf(fmaxf(a0, a1), fmaxf(a2, a3));
            rm = fmaxf(rm, __shfl_xor(rm, 16, 64));
            rm = fmaxf(rm, __shfl_xor(rm, 32, 64));
            float mnew  = fmaxf(m_i, rm);
            float alpha = fast_exp2(m_i - mnew);   // -> 0 on first iter
            m_i = mnew;

            float rs = 0.f;
            #pragma unroll
            for (int nt = 0; nt < 4; ++nt) {
                float e0 = fast_exp2(sv[nt][0] - m_i);
                float e1 = fast_exp2(sv[nt][1] - m_i);
                float e2 = fast_exp2(sv[nt][2] - m_i);
                float e3 = fast_exp2(sv[nt][3] - m_i);
                rs += (e0 + e1) + (e2 + e3);
                uint2 pw;
                pw.x = pack_bf16(e0, e1);
                pw.y = pack_bf16(e2, e3);
                *reinterpret_cast<uint2*>(plds + ((nt * 32 + quad * 8) ^ swz)) = pw;
            }
            rs += __shfl_xor(rs, 16, 64);
            rs += __shfl_xor(rs, 32, 64);
            l_i = fmaf(alpha, l_i, rs);

            #pragma unroll
            for (int nc = 0; nc < 4; ++nc)
                #pragma unroll
                for (int r = 0; r < 4; ++r)
                    oacc[nc][r] *= alpha;

            // Pl is wave-private: intra-wave DS ordering only (keeps staging
            // loads in flight — no barrier here). Same pattern as passing R6.
            asm volatile("s_waitcnt lgkmcnt(0)" ::: "memory");

            // ---- O^T += V^T·P^T  (C: row=d, col=q)
            bf16x8 pf0 = *reinterpret_cast<const bf16x8*>(plds + colA);
            bf16x8 pf1 = *reinterpret_cast<const bf16x8*>(plds + colB);
            #pragma unroll
            for (int nc = 0; nc < 4; ++nc) {
                const char* vr = vt + nc * 2048 + rowB;
                bf16x8 vf0 = *reinterpret_cast<const bf16x8*>(vr + colA);
                bf16x8 vf1 = *reinterpret_cast<const bf16x8*>(vr + colB);
                oacc[nc] = __builtin_amdgcn_mfma_f32_16x16x32_bf16(vf0, pf0, oacc[nc], 0, 0, 0);
                oacc[nc] = __builtin_amdgcn_mfma_f32_16x16x32_bf16(vf1, pf1, oacc[nc], 0, 0, 0);
            }

            __syncthreads();   // drains vmcnt (next tile staged) + lgkmcnt
            cur ^= 1;
        }

        // ---- epilogue: lane owns q=q0+wave*16+m16; O^T rows d -> float4 stores
        float inv = 1.0f / l_i;
        float* op = ogh + (size_t)(q0 + wave * 16 + m16) * D_DIM;
        #pragma unroll
        for (int nc = 0; nc < 4; ++nc) {
            float4 o4;
            o4.x = oacc[nc][0] * inv;
            o4.y = oacc[nc][1] * inv;
            o4.z = oacc[nc][2] * inv;
            o4.w = oacc[nc][3] * inv;
            reinterpret_cast<float4*>(op + nc * 16 + quad * 4)[0] = o4;
        }
    }
}

// ---------------------------------------------------------------------------
// Fallback (R6 kernel, verbatim) — used only if ws_size < 32 MiB.
// ---------------------------------------------------------------------------
__global__ __launch_bounds__(256, 4)
void fa_fwd_fb(const float* __restrict__ qg,
               const float* __restrict__ kg,
               const float* __restrict__ vg,
               float* __restrict__ og)
{
    const int head = blockIdx.x;
    const int pr   = blockIdx.y;
    const int tid  = threadIdx.x;
    const int wave = tid >> 6;
    const int lane = tid & 63;
    const int m16  = lane & 15;
    const int quad = lane >> 4;

    __shared__ unsigned short Kl[TK][LSTR];
    __shared__ unsigned short Vt[D_DIM][LSTR];
    __shared__ unsigned short Pl[4][16][LSTR];

    const size_t hoff = (size_t)head * S_LEN * D_DIM;
    const float* kh = kg + hoff;
    const float* vh = vg + hoff;

    const int ksr = tid >> 2;
    const int ksc = (tid & 3) << 4;
    const int va  = lane >> 3;
    const int vb  = lane & 7;
    const int vrr = wave * 16 + 2 * vb;
    const int vcc = 8 * va;
    const float LOG2E = 1.4426950408889634f;

    for (int pass = 0; pass < 2; ++pass) {
        const int q0 = ((pass == 0) ? pr : (31 - pr)) * TK;

        bf16x8 qf[2];
        {
            const float* qp = qg + hoff + (size_t)(q0 + wave * 16 + m16) * D_DIM + quad * 8;
            #pragma unroll
            for (int c = 0; c < 2; ++c) {
                float4 a = reinterpret_cast<const float4*>(qp + c * 32)[0];
                float4 b = reinterpret_cast<const float4*>(qp + c * 32)[1];
                unsigned int u0 = pack_bf16(a.x * 0.125f, a.y * 0.125f);
                unsigned int u1 = pack_bf16(a.z * 0.125f, a.w * 0.125f);
                unsigned int u2 = pack_bf16(b.x * 0.125f, b.y * 0.125f);
                unsigned int u3 = pack_bf16(b.z * 0.125f, b.w * 0.125f);
                qf[c][0] = (short)(u0 & 0xFFFF); qf[c][1] = (short)(u0 >> 16);
                qf[c][2] = (short)(u1 & 0xFFFF); qf[c][3] = (short)(u1 >> 16);
                qf[c][4] = (short)(u2 & 0xFFFF); qf[c][5] = (short)(u2 >> 16);
                qf[c][6] = (short)(u3 & 0xFFFF); qf[c][7] = (short)(u3 >> 16);
            }
        }

        float m_i = MNEG, l_i = 0.f;
        f32x4 oacc[4];
        #pragma unroll
        for (int nc = 0; nc < 4; ++nc) oacc[nc] = (f32x4){0.f, 0.f, 0.f, 0.f};

        float4 kA, kB, kC, kD, vA, vB, vC, vD;
        {
            const float* kp = kh + (size_t)ksr * D_DIM + ksc;
            kA = reinterpret_cast<const float4*>(kp)[0];
            kB = reinterpret_cast<const float4*>(kp)[1];
            kC = reinterpret_cast<const float4*>(kp)[2];
            kD = reinterpret_cast<const float4*>(kp)[3];
            const float* vp = vh + (size_t)vrr * D_DIM + vcc;
            vA = reinterpret_cast<const float4*>(vp)[0];
            vB = reinterpret_cast<const float4*>(vp)[1];
            vC = reinterpret_cast<const float4*>(vp + D_DIM)[0];
            vD = reinterpret_cast<const float4*>(vp + D_DIM)[1];
        }

        for (int j0 = 0; j0 <= q0; j0 += TK) {
            __syncthreads();
            {
                uint4 w0, w1;
                w0.x = pack_bf16(kA.x, kA.y); w0.y = pack_bf16(kA.z, kA.w);
                w0.z = pack_bf16(kB.x, kB.y); w0.w = pack_bf16(kB.z, kB.w);
                w1.x = pack_bf16(kC.x, kC.y); w1.y = pack_bf16(kC.z, kC.w);
                w1.z = pack_bf16(kD.x, kD.y); w1.w = pack_bf16(kD.z, kD.w);
                *reinterpret_cast<uint4*>(&Kl[ksr][ksc])     = w0;
                *reinterpret_cast<uint4*>(&Kl[ksr][ksc + 8]) = w1;

                float r0[8] = {vA.x, vA.y, vA.z, vA.w, vB.x, vB.y, vB.z, vB.w};
                float r1[8] = {vC.x, vC.y, vC.z, vC.w, vD.x, vD.y, vD.z, vD.w};
                #pragma unroll
                for (int jj = 0; jj < 8; ++jj) {
                    int j = (jj + va) & 7;
                    *reinterpret_cast<unsigned int*>(&Vt[vcc + j][vrr]) = pack_bf16(r0[j], r1[j]);
                }
            }
            __syncthreads();

            if (j0 + TK <= q0) {
                const float* kp = kh + (size_t)(j0 + TK + ksr) * D_DIM + ksc;
                kA = reinterpret_cast<const float4*>(kp)[0];
                kB = reinterpret_cast<const float4*>(kp)[1];
                kC = reinterpret_cast<const float4*>(kp)[2];
                kD = reinterpret_cast<const float4*>(kp)[3];
                const float* vp = vh + (size_t)(j0 + TK + vrr) * D_DIM + vcc;
                vA = reinterpret_cast<const float4*>(vp)[0];
                vB = reinterpret_cast<const float4*>(vp)[1];
                vC = reinterpret_cast<const float4*>(vp + D_DIM)[0];
                vD = reinterpret_cast<const float4*>(vp + D_DIM)[1];
            }

            float sv[4][4];
            #pragma unroll
            for (int nt = 0; nt < 4; ++nt) {
                f32x4 acc = (f32x4){0.f, 0.f, 0.f, 0.f};
                bf16x8 kf0 = *reinterpret_cast<const bf16x8*>(&Kl[nt * 16 + m16][quad * 8]);
                bf16x8 kf1 = *reinterpret_cast<const bf16x8*>(&Kl[nt * 16 + m16][32 + quad * 8]);
                acc = __builtin_amdgcn_mfma_f32_16x16x32_bf16(kf0, qf[0], acc, 0, 0, 0);
                acc = __builtin_amdgcn_mfma_f32_16x16x32_bf16(kf1, qf[1], acc, 0, 0, 0);
                #pragma unroll
                for (int r = 0; r < 4; ++r) sv[nt][r] = acc[r];
            }

            if (j0 == q0) {
                #pragma unroll
                for (int nt = 0; nt < 4; ++nt)
                    #pragma unroll
                    for (int r = 0; r < 4; ++r)
                        if (nt * 16 + quad * 4 + r > wave * 16 + m16) sv[nt][r] = MNEG;
            }

            float a0 = fmaxf(fmaxf(sv[0][0], sv[0][1]), fmaxf(sv[0][2], sv[0][3]));
            float a1 = fmaxf(fmaxf(sv[1][0], sv[1][1]), fmaxf(sv[1][2], sv[1][3]));
            float a2 = fmaxf(fmaxf(sv[2][0], sv[2][1]), fmaxf(sv[2][2], sv[2][3]));
            float a3 = fmaxf(fmaxf(sv[3][0], sv[3][1]), fmaxf(sv[3][2], sv[3][3]));
            float rm = fmaxf(fmaxf(a0, a1), fmaxf(a2, a3));
            rm = fmaxf(rm, __shfl_xor(rm, 16, 64));
            rm = fmaxf(rm, __shfl_xor(rm, 32, 64));
            float mnew  = fmaxf(m_i, rm);
            float alpha = fast_exp2((m_i - mnew) * LOG2E);
            float msc   = mnew * LOG2E;
            m_i = mnew;

            float rs = 0.f;
            #pragma unroll
            for (int nt = 0; nt < 4; ++nt) {
                float e0 = fast_exp2(fmaf(sv[nt][0], LOG2E, -msc));
                float e1 = fast_exp2(fmaf(sv[nt][1], LOG2E, -msc));
                float e2 = fast_exp2(fmaf(sv[nt][2], LOG2E, -msc));
                float e3 = fast_exp2(fmaf(sv[nt][3], LOG2E, -msc));
                rs += (e0 + e1) + (e2 + e3);
                uint2 pw;
                pw.x = pack_bf16(e0, e1);
                pw.y = pack_bf16(e2, e3);
                *reinterpret_cast<uint2*>(&Pl[wave][m16][nt * 16 + quad * 4]) = pw;
            }
            rs += __shfl_xor(rs, 16, 64);
            rs += __shfl_xor(rs, 32, 64);
            l_i = fmaf(alpha, l_i, rs);

            #pragma unroll
            for (int nc = 0; nc < 4; ++nc)
                #pragma unroll
                for (int r = 0; r < 4; ++r)
                    oacc[nc][r] *= alpha;

            asm volatile("s_waitcnt lgkmcnt(0)" ::: "memory");

            bf16x8 pf0 = *reinterpret_cast<const bf16x8*>(&Pl[wave][m16][quad * 8]);
            bf16x8 pf1 = *reinterpret_cast<const bf16x8*>(&Pl[wave][m16][32 + quad * 8]);
            #pragma unroll
            for (int nc = 0; nc < 4; ++nc) {
                bf16x8 vf0 = *reinterpret_cast<const bf16x8*>(&Vt[nc * 16 + m16][quad * 8]);
                bf16x8 vf1 = *reinterpret_cast<const bf16x8*>(&Vt[nc * 16 + m16][32 + quad * 8]);
                oacc[nc] = __builtin_amdgcn_mfma_f32_16x16x32_bf16(vf0, pf0, oacc[nc], 0, 0, 0);
                oacc[nc] = __builtin_amdgcn_mfma_f32_16x16x32_bf16(vf1, pf1, oacc[nc], 0, 0, 0);
            }
        }

        float inv = 1.0f / l_i;
        float* op = og + hoff + (size_t)(q0 + wave * 16 + m16) * D_DIM;
        #pragma unroll
        for (int nc = 0; nc < 4; ++nc) {
            float4 o4;
            o4.x = oacc[nc][0] * inv;
            o4.y = oacc[nc][1] * inv;
            o4.z = oacc[nc][2] * inv;
            o4.w = oacc[nc][3] * inv;
            reinterpret_cast<float4*>(op + nc * 16 + quad * 4)[0] = o4;
        }
    }
}

extern "C" void kernel_launch(void* const* d_in, const int* in_sizes, int n_in,
                              void* d_out, int out_size, void* d_ws, size_t ws_size,
                              hipStream_t stream) {
    const float* q = (const float*)d_in[0];
    const float* k = (const float*)d_in[1];
    const float* v = (const float*)d_in[2];
    float* o = (float*)d_out;
    const size_t kvShorts = (size_t)NHEAD * S_LEN * D_DIM;           // 8.39M
    const size_t wsNeed   = 2 * kvShorts * sizeof(unsigned short);   // 32 MiB
    dim3 grid(NHEAD, 16);
    if (d_ws != nullptr && ws_size >= wsNeed) {
        unsigned short* kb = (unsigned short*)d_ws;
        unsigned short* vb = kb + kvShorts;
        fa_prep<<<PREP_KBLK + 512, 256, 0, stream>>>(k, v, kb, vb);
        fa_fwd<<<grid, 256, 0, stream>>>(q, kb, vb, o);
    } else {
        fa_fwd_fb<<<grid, 256, 0, stream>>>(q, k, v, o);
    }
}

// Round 3
// 206.873 us; speedup vs baseline: 1.0906x; 1.0016x over previous
//
#include <hip/hip_runtime.h>
#include <math.h>

// B=4, H=16, S=2048, D=64 causal attention. fp32 in, fp32 out.
// R9 = R8 + defer-max rescale (T13) + v_max3 fmax tree. Bisect step: R7's
// failure is attributed to v_cvt_pk_bf16_f32 (pair-swap-magnitude error);
// defer-max re-added alone here to confirm. P pack stays pack_bf16 (proven).
//  - fa_prep: K -> bf16 [head][kv][d], chunk ^= kv&7 (T2); V -> bf16 transposed
//    tile-major [head][tile][d][64kv], chunk ^= d&7. O(S) conversion, once.
//  - fa_fwd: K/V tiles staged via global_load_lds (zero staging VALU), double
//    buffered, swizzled reads bank-balanced; log2-domain scores (LOG2E folded
//    into Q scale); defer-max: skip O/l rescale while tile max within THR.
//  Fallback to R6 kernel if ws_size < 32 MiB.

#define S_LEN 2048
#define D_DIM 64
#define TK 64
#define NHEAD 64
#define MNEG -30000.0f
#define DEFER_THR 12.0f   // log2 domain: P bounded by 2^12; bf16 rel-err unchanged
#define LSTR 72           // fallback kernel only
#define PREP_KBLK 4096

typedef __attribute__((ext_vector_type(8))) short bf16x8;
typedef __attribute__((ext_vector_type(4))) float f32x4;

static __device__ __forceinline__ float fast_exp2(float x) {
#if __has_builtin(__builtin_amdgcn_exp2f)
    return __builtin_amdgcn_exp2f(x);   // v_exp_f32: 2^x, large-negative -> 0
#else
    float r;
    asm volatile("v_exp_f32 %0, %1\n\ts_nop 1" : "=v"(r) : "v"(x));
    return r;
#endif
}

// clang fuses nested fmaxf to v_max3_f32 (exact)
static __device__ __forceinline__ float fmax3(float a, float b, float c) {
    return fmaxf(fmaxf(a, b), c);
}

// round-half-up fp32->bf16 pair, packed into one dword (a=low, b=high)
static __device__ __forceinline__ unsigned int pack_bf16(float a, float b) {
    union { float f; unsigned int u; } ca, cb;
    ca.f = a; cb.f = b;
    unsigned int ua = ca.u + 0x8000u;
    unsigned int ub = cb.u + 0x8000u;
    return (ua >> 16) | (ub & 0xFFFF0000u);
}

typedef const __attribute__((address_space(1))) unsigned int* gas1_t;
typedef __attribute__((address_space(3))) unsigned int* las3_t;
// async global->LDS, 16B per lane. LDS dest is wave-uniform base (+lane*16 in HW).
static __device__ __forceinline__ void stage16(const void* g, void* l) {
    __builtin_amdgcn_global_load_lds((gas1_t)g, (las3_t)l, 16, 0, 0);
}

// ---------------------------------------------------------------------------
// Prep: K -> kb (bf16, row-chunk-swizzled), V -> vb (bf16, transposed,
// tile-major, row-chunk-swizzled). Blocks [0,PREP_KBLK): K. Rest: V.
// ---------------------------------------------------------------------------
__global__ __launch_bounds__(256)
void fa_prep(const float* __restrict__ kg, const float* __restrict__ vg,
             unsigned short* __restrict__ kb, unsigned short* __restrict__ vb)
{
    const int tid = threadIdx.x;
    const int bid = blockIdx.x;
    if (bid < PREP_KBLK) {
        // one 16B chunk (8 d-elems) of one K row per thread
        const int cid = bid * 256 + tid;          // (head*S + kv)*8 + ch
        const int ch  = cid & 7;
        const int row = cid >> 3;                 // head*S + kv
        const int kv  = row & (S_LEN - 1);
        const float4* s = reinterpret_cast<const float4*>(kg + (size_t)row * D_DIM + ch * 8);
        float4 a = s[0], b = s[1];
        uint4 w;
        w.x = pack_bf16(a.x, a.y); w.y = pack_bf16(a.z, a.w);
        w.z = pack_bf16(b.x, b.y); w.w = pack_bf16(b.z, b.w);
        const int dst = ch ^ (kv & 7);            // T2 swizzle
        *reinterpret_cast<uint4*>(kb + (size_t)row * D_DIM + dst * 8) = w;
    } else {
        // one 64x64 V tile per wave; lane = (kv-group kg8, d-group dg)
        const int wv   = (bid - PREP_KBLK) * 4 + (tid >> 6);  // head*32 + t
        const int lane = tid & 63;
        const int kg8  = lane >> 3;
        const int dg   = lane & 7;
        const float* s = vg + ((size_t)wv * TK + kg8 * 8) * D_DIM + dg * 8;
        float va[8][8];                            // [kv in group][d in group]
        #pragma unroll
        for (int i = 0; i < 8; ++i) {
            const float4* sp = reinterpret_cast<const float4*>(s + (size_t)i * D_DIM);
            float4 x = sp[0], y = sp[1];
            va[i][0] = x.x; va[i][1] = x.y; va[i][2] = x.z; va[i][3] = x.w;
            va[i][4] = y.x; va[i][5] = y.y; va[i][6] = y.z; va[i][7] = y.w;
        }
        unsigned short* db = vb + (size_t)wv * (TK * D_DIM);  // tile base (8 KB)
        #pragma unroll
        for (int j = 0; j < 8; ++j) {
            const int d = dg * 8 + j;             // d&7 == j
            uint4 w;
            w.x = pack_bf16(va[0][j], va[1][j]);
            w.y = pack_bf16(va[2][j], va[3][j]);
            w.z = pack_bf16(va[4][j], va[5][j]);
            w.w = pack_bf16(va[6][j], va[7][j]);
            *reinterpret_cast<uint4*>(db + d * D_DIM + 8 * (kg8 ^ j)) = w;
        }
    }
}

// ---------------------------------------------------------------------------
// Main: flash fwd, S^T formulation, bf16 K/V from workspace.
// LDS = 2*8K (K dbuf) + 2*8K (V dbuf) + 8K (P) = 40960 B -> 4 blocks/CU.
// ---------------------------------------------------------------------------
__global__ __launch_bounds__(256, 4)
void fa_fwd(const float* __restrict__ qg,
            const unsigned short* __restrict__ kb,
            const unsigned short* __restrict__ vb,
            float* __restrict__ og)
{
    const int head = blockIdx.x;          // fast dim -> XCD spread
    const int pr   = blockIdx.y;          // 0..15: q-tiles {pr, 31-pr}
    const int tid  = threadIdx.x;
    const int wave = tid >> 6;
    const int lane = tid & 63;
    const int m16  = lane & 15;
    const int quad = lane >> 4;

    __shared__ unsigned short Kl[2][TK * D_DIM];   // swizzled [kv][d] bf16
    __shared__ unsigned short Vt[2][TK * D_DIM];   // swizzled [d][kv] bf16
    __shared__ unsigned short Pl[4][16 * TK];      // per-wave swizzled [q][kv]

    const size_t hoff = (size_t)head * S_LEN * D_DIM;
    const unsigned short* kbh = kb + hoff;
    const unsigned short* vbh = vb + hoff;
    float* __restrict__ ogh = og + hoff;

    // swizzled byte columns within a 128B row (row&7 == m16&7 for all rows used)
    const int swz  = (m16 & 7) << 4;
    const int colA = (quad * 16) ^ swz;
    const int colB = (64 + quad * 16) ^ swz;
    const int rowB = m16 * 128;
    const int sgo  = wave * 512 + lane * 8;   // staging src offset (shorts)

    char* klds = (char*)&Kl[0][0];
    char* vlds = (char*)&Vt[0][0];
    char* plds = (char*)&Pl[0][0] + wave * 2048 + m16 * 128;
    char* kw   = klds + wave * 1024;          // wave-uniform stage dest (buf 0)
    char* vw   = vlds + wave * 1024;

    const float QSC = 0.18033688011112042f;   // 1/8 * log2(e): scores in log2 domain

    for (int pass = 0; pass < 2; ++pass) {
        const int q0 = ((pass == 0) ? pr : (31 - pr)) * TK;
        const int T  = q0 >> 6;               // last (diagonal) tile index

        // ---- Q fragment (B operand): n=q=m16, k=d=quad*8+j; scaled 1/8*log2e
        bf16x8 qf[2];
        {
            const float* qp = qg + hoff + (size_t)(q0 + wave * 16 + m16) * D_DIM + quad * 8;
            #pragma unroll
            for (int c = 0; c < 2; ++c) {
                float4 a = reinterpret_cast<const float4*>(qp + c * 32)[0];
                float4 b = reinterpret_cast<const float4*>(qp + c * 32)[1];
                unsigned int u0 = pack_bf16(a.x * QSC, a.y * QSC);
                unsigned int u1 = pack_bf16(a.z * QSC, a.w * QSC);
                unsigned int u2 = pack_bf16(b.x * QSC, b.y * QSC);
                unsigned int u3 = pack_bf16(b.z * QSC, b.w * QSC);
                qf[c][0] = (short)(u0 & 0xFFFF); qf[c][1] = (short)(u0 >> 16);
                qf[c][2] = (short)(u1 & 0xFFFF); qf[c][3] = (short)(u1 >> 16);
                qf[c][4] = (short)(u2 & 0xFFFF); qf[c][5] = (short)(u2 >> 16);
                qf[c][6] = (short)(u3 & 0xFFFF); qf[c][7] = (short)(u3 >> 16);
            }
        }

        float m_i = MNEG, l_i = 0.f;
        f32x4 oacc[4];
        #pragma unroll
        for (int nc = 0; nc < 4; ++nc) oacc[nc] = (f32x4){0.f, 0.f, 0.f, 0.f};

        // ---- prologue: stage tile 0 into buf 0 (4x global_load_lds / wave)
        {
            const unsigned short* ks = kbh + sgo;
            const unsigned short* vs = vbh + sgo;
            stage16(ks,        kw);
            stage16(ks + 2048, kw + 4096);
            stage16(vs,        vw);
            stage16(vs + 2048, vw + 4096);
        }
        __syncthreads();   // compiler drains vmcnt(0) before s_barrier

        int cur = 0;
        for (int t = 0; t <= T; ++t) {
            // ---- issue next-tile stage first: HBM/L2 latency hides under compute
            if (t < T) {
                const unsigned short* ks = kbh + (size_t)(t + 1) * 4096 + sgo;
                const unsigned short* vs = vbh + (size_t)(t + 1) * 4096 + sgo;
                const int nb = (cur ^ 1) * 8192;
                stage16(ks,        kw + nb);
                stage16(ks + 2048, kw + nb + 4096);
                stage16(vs,        vw + nb);
                stage16(vs + 2048, vw + nb + 4096);
            }

            const char* kt = klds + cur * 8192;
            const char* vt = vlds + cur * 8192;

            // ---- S^T = K·Q^T  (C: row=kv=nt*16+quad*4+r, col=q=m16), log2 domain
            float sv[4][4];
            #pragma unroll
            for (int nt = 0; nt < 4; ++nt) {
                f32x4 acc = (f32x4){0.f, 0.f, 0.f, 0.f};
                const char* kr = kt + nt * 2048 + rowB;
                bf16x8 kf0 = *reinterpret_cast<const bf16x8*>(kr + colA);
                bf16x8 kf1 = *reinterpret_cast<const bf16x8*>(kr + colB);
                acc = __builtin_amdgcn_mfma_f32_16x16x32_bf16(kf0, qf[0], acc, 0, 0, 0);
                acc = __builtin_amdgcn_mfma_f32_16x16x32_bf16(kf1, qf[1], acc, 0, 0, 0);
                #pragma unroll
                for (int r = 0; r < 4; ++r) sv[nt][r] = acc[r];
            }

            // ---- causal mask (diagonal tile only)
            if (t == T) {
                #pragma unroll
                for (int nt = 0; nt < 4; ++nt)
                    #pragma unroll
                    for (int r = 0; r < 4; ++r)
                        if (nt * 16 + quad * 4 + r > wave * 16 + m16) sv[nt][r] = MNEG;
            }

            // ---- row max: v_max3 tree (8 ops, depth 3), then quad reduce
            float t0 = fmax3(sv[0][0], sv[0][1], sv[0][2]);
            float t1 = fmax3(sv[0][3], sv[1][0], sv[1][1]);
            float t2 = fmax3(sv[1][2], sv[1][3], sv[2][0]);
            float t3 = fmax3(sv[2][1], sv[2][2], sv[2][3]);
            float t4 = fmax3(sv[3][0], sv[3][1], sv[3][2]);
            float u0 = fmax3(t0, t1, t2);
            float u1 = fmax3(t3, t4, sv[3][3]);
            float rm = fmaxf(u0, u1);
            rm = fmaxf(rm, __shfl_xor(rm, 16, 64));
            rm = fmaxf(rm, __shfl_xor(rm, 32, 64));

            // ---- defer-max (T13): rescale only when tile max exceeds m_i+THR.
            // rm is quad-reduced, so all 4 lanes of a q agree; branch wave-uniform.
            if (__any(rm > m_i + DEFER_THR)) {
                float mnew  = fmaxf(m_i, rm);           // per-lane
                float alpha = fast_exp2(m_i - mnew);    // -> 0 on first iter
                l_i *= alpha;
                #pragma unroll
                for (int nc = 0; nc < 4; ++nc)
                    #pragma unroll
                    for (int r = 0; r < 4; ++r) oacc[nc][r] *= alpha;
                m_i = mnew;
            }

            float rs = 0.f;
            #pragma unroll
            for (int nt = 0; nt < 4; ++nt) {
                float e0 = fast_exp2(sv[nt][0] - m_i);   // bounded by 2^DEFER_THR
                float e1 = fast_exp2(sv[nt][1] - m_i);
                float e2 = fast_exp2(sv[nt][2] - m_i);
                float e3 = fast_exp2(sv[nt][3] - m_i);
                rs += (e0 + e1) + (e2 + e3);
                uint2 pw;
                pw.x = pack_bf16(e0, e1);
                pw.y = pack_bf16(e2, e3);
                *reinterpret_cast<uint2*>(plds + ((nt * 32 + quad * 8) ^ swz)) = pw;
            }
            rs += __shfl_xor(rs, 16, 64);
            rs += __shfl_xor(rs, 32, 64);
            l_i += rs;

            // Pl is wave-private: intra-wave DS ordering only (keeps staging
            // loads in flight — no barrier here). Same pattern as passing R6/R8.
            asm volatile("s_waitcnt lgkmcnt(0)" ::: "memory");

            // ---- O^T += V^T·P^T  (C: row=d, col=q)
            bf16x8 pf0 = *reinterpret_cast<const bf16x8*>(plds + colA);
            bf16x8 pf1 = *reinterpret_cast<const bf16x8*>(plds + colB);
            #pragma unroll
            for (int nc = 0; nc < 4; ++nc) {
                const char* vr = vt + nc * 2048 + rowB;
                bf16x8 vf0 = *reinterpret_cast<const bf16x8*>(vr + colA);
                bf16x8 vf1 = *reinterpret_cast<const bf16x8*>(vr + colB);
                oacc[nc] = __builtin_amdgcn_mfma_f32_16x16x32_bf16(vf0, pf0, oacc[nc], 0, 0, 0);
                oacc[nc] = __builtin_amdgcn_mfma_f32_16x16x32_bf16(vf1, pf1, oacc[nc], 0, 0, 0);
            }

            __syncthreads();   // drains vmcnt (next tile staged) + lgkmcnt
            cur ^= 1;
        }

        // ---- epilogue: lane owns q=q0+wave*16+m16; O^T rows d -> float4 stores
        float inv = 1.0f / l_i;
        float* op = ogh + (size_t)(q0 + wave * 16 + m16) * D_DIM;
        #pragma unroll
        for (int nc = 0; nc < 4; ++nc) {
            float4 o4;
            o4.x = oacc[nc][0] * inv;
            o4.y = oacc[nc][1] * inv;
            o4.z = oacc[nc][2] * inv;
            o4.w = oacc[nc][3] * inv;
            reinterpret_cast<float4*>(op + nc * 16 + quad * 4)[0] = o4;
        }
    }
}

// ---------------------------------------------------------------------------
// Fallback (R6 kernel, verbatim) — used only if ws_size < 32 MiB.
// ---------------------------------------------------------------------------
__global__ __launch_bounds__(256, 4)
void fa_fwd_fb(const float* __restrict__ qg,
               const float* __restrict__ kg,
               const float* __restrict__ vg,
               float* __restrict__ og)
{
    const int head = blockIdx.x;
    const int pr   = blockIdx.y;
    const int tid  = threadIdx.x;
    const int wave = tid >> 6;
    const int lane = tid & 63;
    const int m16  = lane & 15;
    const int quad = lane >> 4;

    __shared__ unsigned short Kl[TK][LSTR];
    __shared__ unsigned short Vt[D_DIM][LSTR];
    __shared__ unsigned short Pl[4][16][LSTR];

    const size_t hoff = (size_t)head * S_LEN * D_DIM;
    const float* kh = kg + hoff;
    const float* vh = vg + hoff;

    const int ksr = tid >> 2;
    const int ksc = (tid & 3) << 4;
    const int va  = lane >> 3;
    const int vb  = lane & 7;
    const int vrr = wave * 16 + 2 * vb;
    const int vcc = 8 * va;
    const float LOG2E = 1.4426950408889634f;

    for (int pass = 0; pass < 2; ++pass) {
        const int q0 = ((pass == 0) ? pr : (31 - pr)) * TK;

        bf16x8 qf[2];
        {
            const float* qp = qg + hoff + (size_t)(q0 + wave * 16 + m16) * D_DIM + quad * 8;
            #pragma unroll
            for (int c = 0; c < 2; ++c) {
                float4 a = reinterpret_cast<const float4*>(qp + c * 32)[0];
                float4 b = reinterpret_cast<const float4*>(qp + c * 32)[1];
                unsigned int u0 = pack_bf16(a.x * 0.125f, a.y * 0.125f);
                unsigned int u1 = pack_bf16(a.z * 0.125f, a.w * 0.125f);
                unsigned int u2 = pack_bf16(b.x * 0.125f, b.y * 0.125f);
                unsigned int u3 = pack_bf16(b.z * 0.125f, b.w * 0.125f);
                qf[c][0] = (short)(u0 & 0xFFFF); qf[c][1] = (short)(u0 >> 16);
                qf[c][2] = (short)(u1 & 0xFFFF); qf[c][3] = (short)(u1 >> 16);
                qf[c][4] = (short)(u2 & 0xFFFF); qf[c][5] = (short)(u2 >> 16);
                qf[c][6] = (short)(u3 & 0xFFFF); qf[c][7] = (short)(u3 >> 16);
            }
        }

        float m_i = MNEG, l_i = 0.f;
        f32x4 oacc[4];
        #pragma unroll
        for (int nc = 0; nc < 4; ++nc) oacc[nc] = (f32x4){0.f, 0.f, 0.f, 0.f};

        float4 kA, kB, kC, kD, vA, vB, vC, vD;
        {
            const float* kp = kh + (size_t)ksr * D_DIM + ksc;
            kA = reinterpret_cast<const float4*>(kp)[0];
            kB = reinterpret_cast<const float4*>(kp)[1];
            kC = reinterpret_cast<const float4*>(kp)[2];
            kD = reinterpret_cast<const float4*>(kp)[3];
            const float* vp = vh + (size_t)vrr * D_DIM + vcc;
            vA = reinterpret_cast<const float4*>(vp)[0];
            vB = reinterpret_cast<const float4*>(vp)[1];
            vC = reinterpret_cast<const float4*>(vp + D_DIM)[0];
            vD = reinterpret_cast<const float4*>(vp + D_DIM)[1];
        }

        for (int j0 = 0; j0 <= q0; j0 += TK) {
            __syncthreads();
            {
                uint4 w0, w1;
                w0.x = pack_bf16(kA.x, kA.y); w0.y = pack_bf16(kA.z, kA.w);
                w0.z = pack_bf16(kB.x, kB.y); w0.w = pack_bf16(kB.z, kB.w);
                w1.x = pack_bf16(kC.x, kC.y); w1.y = pack_bf16(kC.z, kC.w);
                w1.z = pack_bf16(kD.x, kD.y); w1.w = pack_bf16(kD.z, kD.w);
                *reinterpret_cast<uint4*>(&Kl[ksr][ksc])     = w0;
                *reinterpret_cast<uint4*>(&Kl[ksr][ksc + 8]) = w1;

                float r0[8] = {vA.x, vA.y, vA.z, vA.w, vB.x, vB.y, vB.z, vB.w};
                float r1[8] = {vC.x, vC.y, vC.z, vC.w, vD.x, vD.y, vD.z, vD.w};
                #pragma unroll
                for (int jj = 0; jj < 8; ++jj) {
                    int j = (jj + va) & 7;
                    *reinterpret_cast<unsigned int*>(&Vt[vcc + j][vrr]) = pack_bf16(r0[j], r1[j]);
                }
            }
            __syncthreads();

            if (j0 + TK <= q0) {
                const float* kp = kh + (size_t)(j0 + TK + ksr) * D_DIM + ksc;
                kA = reinterpret_cast<const float4*>(kp)[0];
                kB = reinterpret_cast<const float4*>(kp)[1];
                kC = reinterpret_cast<const float4*>(kp)[2];
                kD = reinterpret_cast<const float4*>(kp)[3];
                const float* vp = vh + (size_t)(j0 + TK + vrr) * D_DIM + vcc;
                vA = reinterpret_cast<const float4*>(vp)[0];
                vB = reinterpret_cast<const float4*>(vp)[1];
                vC = reinterpret_cast<const float4*>(vp + D_DIM)[0];
                vD = reinterpret_cast<const float4*>(vp + D_DIM)[1];
            }

            float sv[4][4];
            #pragma unroll
            for (int nt = 0; nt < 4; ++nt) {
                f32x4 acc = (f32x4){0.f, 0.f, 0.f, 0.f};
                bf16x8 kf0 = *reinterpret_cast<const bf16x8*>(&Kl[nt * 16 + m16][quad * 8]);
                bf16x8 kf1 = *reinterpret_cast<const bf16x8*>(&Kl[nt * 16 + m16][32 + quad * 8]);
                acc = __builtin_amdgcn_mfma_f32_16x16x32_bf16(kf0, qf[0], acc, 0, 0, 0);
                acc = __builtin_amdgcn_mfma_f32_16x16x32_bf16(kf1, qf[1], acc, 0, 0, 0);
                #pragma unroll
                for (int r = 0; r < 4; ++r) sv[nt][r] = acc[r];
            }

            if (j0 == q0) {
                #pragma unroll
                for (int nt = 0; nt < 4; ++nt)
                    #pragma unroll
                    for (int r = 0; r < 4; ++r)
                        if (nt * 16 + quad * 4 + r > wave * 16 + m16) sv[nt][r] = MNEG;
            }

            float a0 = fmaxf(fmaxf(sv[0][0], sv[0][1]), fmaxf(sv[0][2], sv[0][3]));
            float a1 = fmaxf(fmaxf(sv[1][0], sv[1][1]), fmaxf(sv[1][2], sv[1][3]));
            float a2 = fmaxf(fmaxf(sv[2][0], sv[2][1]), fmaxf(sv[2][2], sv[2][3]));
            float a3 = fmaxf(fmaxf(sv[3][0], sv[3][1]), fmaxf(sv[3][2], sv[3][3]));
            float rm = fmaxf(fmaxf(a0, a1), fmaxf(a2, a3));
            rm = fmaxf(rm, __shfl_xor(rm, 16, 64));
            rm = fmaxf(rm, __shfl_xor(rm, 32, 64));
            float mnew  = fmaxf(m_i, rm);
            float alpha = fast_exp2((m_i - mnew) * LOG2E);
            float msc   = mnew * LOG2E;
            m_i = mnew;

            float rs = 0.f;
            #pragma unroll
            for (int nt = 0; nt < 4; ++nt) {
                float e0 = fast_exp2(fmaf(sv[nt][0], LOG2E, -msc));
                float e1 = fast_exp2(fmaf(sv[nt][1], LOG2E, -msc));
                float e2 = fast_exp2(fmaf(sv[nt][2], LOG2E, -msc));
                float e3 = fast_exp2(fmaf(sv[nt][3], LOG2E, -msc));
                rs += (e0 + e1) + (e2 + e3);
                uint2 pw;
                pw.x = pack_bf16(e0, e1);
                pw.y = pack_bf16(e2, e3);
                *reinterpret_cast<uint2*>(&Pl[wave][m16][nt * 16 + quad * 4]) = pw;
            }
            rs += __shfl_xor(rs, 16, 64);
            rs += __shfl_xor(rs, 32, 64);
            l_i = fmaf(alpha, l_i, rs);

            #pragma unroll
            for (int nc = 0; nc < 4; ++nc)
                #pragma unroll
                for (int r = 0; r < 4; ++r)
                    oacc[nc][r] *= alpha;

            asm volatile("s_waitcnt lgkmcnt(0)" ::: "memory");

            bf16x8 pf0 = *reinterpret_cast<const bf16x8*>(&Pl[wave][m16][quad * 8]);
            bf16x8 pf1 = *reinterpret_cast<const bf16x8*>(&Pl[wave][m16][32 + quad * 8]);
            #pragma unroll
            for (int nc = 0; nc < 4; ++nc) {
                bf16x8 vf0 = *reinterpret_cast<const bf16x8*>(&Vt[nc * 16 + m16][quad * 8]);
                bf16x8 vf1 = *reinterpret_cast<const bf16x8*>(&Vt[nc * 16 + m16][32 + quad * 8]);
                oacc[nc] = __builtin_amdgcn_mfma_f32_16x16x32_bf16(vf0, pf0, oacc[nc], 0, 0, 0);
                oacc[nc] = __builtin_amdgcn_mfma_f32_16x16x32_bf16(vf1, pf1, oacc[nc], 0, 0, 0);
            }
        }

        float inv = 1.0f / l_i;
        float* op = og + hoff + (size_t)(q0 + wave * 16 + m16) * D_DIM;
        #pragma unroll
        for (int nc = 0; nc < 4; ++nc) {
            float4 o4;
            o4.x = oacc[nc][0] * inv;
            o4.y = oacc[nc][1] * inv;
            o4.z = oacc[nc][2] * inv;
            o4.w = oacc[nc][3] * inv;
            reinterpret_cast<float4*>(op + nc * 16 + quad * 4)[0] = o4;
        }
    }
}

extern "C" void kernel_launch(void* const* d_in, const int* in_sizes, int n_in,
                              void* d_out, int out_size, void* d_ws, size_t ws_size,
                              hipStream_t stream) {
    const float* q = (const float*)d_in[0];
    const float* k = (const float*)d_in[1];
    const float* v = (const float*)d_in[2];
    float* o = (float*)d_out;
    const size_t kvShorts = (size_t)NHEAD * S_LEN * D_DIM;           // 8.39M
    const size_t wsNeed   = 2 * kvShorts * sizeof(unsigned short);   // 32 MiB
    dim3 grid(NHEAD, 16);
    if (d_ws != nullptr && ws_size >= wsNeed) {
        unsigned short* kb = (unsigned short*)d_ws;
        unsigned short* vb = kb + kvShorts;
        fa_prep<<<PREP_KBLK + 512, 256, 0, stream>>>(k, v, kb, vb);
        fa_fwd<<<grid, 256, 0, stream>>>(q, kb, vb, o);
    } else {
        fa_fwd_fb<<<grid, 256, 0, stream>>>(q, k, v, o);
    }
}

// Round 4
// 201.005 us; speedup vs baseline: 1.1225x; 1.0292x over previous
//
#include <hip/hip_runtime.h>
#include <math.h>

// B=4, H=16, S=2048, D=64 causal attention. fp32 in, fp32 out.
// R10 = R9 + three VALU/schedule cuts (theory: VALU-issue still largest pipe):
//  1. P pack via v_perm_b32 (3 ops/pair vs 5; BIT-IDENTICAL to pack_bf16 —
//     NOT the R7-failing v_cvt_pk asm, which is convicted and banned).
//  2. -m_i folded into QK MFMA C-operand (mc): sv emerges relative; the
//     16 per-element subs run only on rescale tiles (~10% with defer-max).
//     m tracked relatively; first tile always rescales (sv ~ +1000 > THR).
//  3. s_setprio(1) around MFMA clusters (T5; 4 independent blocks/CU =
//     the m191-positive regime).
// Carried: fa_prep O(S) bf16 conversion (K row-swizzled, V transposed
// tile-major), global_load_lds staging, double-buffer, T2 swizzle,
// log2-domain scores, defer-max (T13), v_max3 tree.
// Fallback to R6 kernel if ws_size < 32 MiB.

#define S_LEN 2048
#define D_DIM 64
#define TK 64
#define NHEAD 64
#define MASKV -30000.0f   // causal mask value (absolute, always underflows exp2)
#define MINIT 1000.0f     // initial -m_i: sv(tile0) ~ +1000 -> forces rescale
#define DEFER_THR 12.0f   // log2 domain: P bounded by 2^12
#define MNEG -30000.0f    // fallback kernel only
#define LSTR 72           // fallback kernel only
#define PREP_KBLK 4096

typedef __attribute__((ext_vector_type(8))) short bf16x8;
typedef __attribute__((ext_vector_type(4))) float f32x4;

static __device__ __forceinline__ float fast_exp2(float x) {
#if __has_builtin(__builtin_amdgcn_exp2f)
    return __builtin_amdgcn_exp2f(x);   // v_exp_f32: 2^x, large-negative -> 0
#else
    float r;
    asm volatile("v_exp_f32 %0, %1\n\ts_nop 1" : "=v"(r) : "v"(x));
    return r;
#endif
}

// clang fuses nested fmaxf to v_max3_f32 (exact)
static __device__ __forceinline__ float fmax3(float a, float b, float c) {
    return fmaxf(fmaxf(a, b), c);
}

// round-half-up fp32->bf16 pair, packed into one dword (a=low, b=high)
static __device__ __forceinline__ unsigned int pack_bf16(float a, float b) {
    union { float f; unsigned int u; } ca, cb;
    ca.f = a; cb.f = b;
    unsigned int ua = ca.u + 0x8000u;
    unsigned int ub = cb.u + 0x8000u;
    return (ua >> 16) | (ub & 0xFFFF0000u);
}

// same bits as pack_bf16, 3 VALU ops: 2 adds + v_perm_b32 byte select.
// result bytes = [a.b2, a.b3, b.b2, b.b3] (a=low half, b=high half).
static __device__ __forceinline__ unsigned int pack_bf16_fast(float a, float b) {
#if __has_builtin(__builtin_amdgcn_perm)
    union { float f; unsigned int u; } ca, cb;
    ca.f = a; cb.f = b;
    return __builtin_amdgcn_perm(cb.u + 0x8000u, ca.u + 0x8000u, 0x07060302u);
#else
    return pack_bf16(a, b);
#endif
}

typedef const __attribute__((address_space(1))) unsigned int* gas1_t;
typedef __attribute__((address_space(3))) unsigned int* las3_t;
// async global->LDS, 16B per lane. LDS dest is wave-uniform base (+lane*16 in HW).
static __device__ __forceinline__ void stage16(const void* g, void* l) {
    __builtin_amdgcn_global_load_lds((gas1_t)g, (las3_t)l, 16, 0, 0);
}

// ---------------------------------------------------------------------------
// Prep: K -> kb (bf16, row-chunk-swizzled), V -> vb (bf16, transposed,
// tile-major, row-chunk-swizzled). Blocks [0,PREP_KBLK): K. Rest: V.
// ---------------------------------------------------------------------------
__global__ __launch_bounds__(256)
void fa_prep(const float* __restrict__ kg, const float* __restrict__ vg,
             unsigned short* __restrict__ kb, unsigned short* __restrict__ vb)
{
    const int tid = threadIdx.x;
    const int bid = blockIdx.x;
    if (bid < PREP_KBLK) {
        // one 16B chunk (8 d-elems) of one K row per thread
        const int cid = bid * 256 + tid;          // (head*S + kv)*8 + ch
        const int ch  = cid & 7;
        const int row = cid >> 3;                 // head*S + kv
        const int kv  = row & (S_LEN - 1);
        const float4* s = reinterpret_cast<const float4*>(kg + (size_t)row * D_DIM + ch * 8);
        float4 a = s[0], b = s[1];
        uint4 w;
        w.x = pack_bf16(a.x, a.y); w.y = pack_bf16(a.z, a.w);
        w.z = pack_bf16(b.x, b.y); w.w = pack_bf16(b.z, b.w);
        const int dst = ch ^ (kv & 7);            // T2 swizzle
        *reinterpret_cast<uint4*>(kb + (size_t)row * D_DIM + dst * 8) = w;
    } else {
        // one 64x64 V tile per wave; lane = (kv-group kg8, d-group dg)
        const int wv   = (bid - PREP_KBLK) * 4 + (tid >> 6);  // head*32 + t
        const int lane = tid & 63;
        const int kg8  = lane >> 3;
        const int dg   = lane & 7;
        const float* s = vg + ((size_t)wv * TK + kg8 * 8) * D_DIM + dg * 8;
        float va[8][8];                            // [kv in group][d in group]
        #pragma unroll
        for (int i = 0; i < 8; ++i) {
            const float4* sp = reinterpret_cast<const float4*>(s + (size_t)i * D_DIM);
            float4 x = sp[0], y = sp[1];
            va[i][0] = x.x; va[i][1] = x.y; va[i][2] = x.z; va[i][3] = x.w;
            va[i][4] = y.x; va[i][5] = y.y; va[i][6] = y.z; va[i][7] = y.w;
        }
        unsigned short* db = vb + (size_t)wv * (TK * D_DIM);  // tile base (8 KB)
        #pragma unroll
        for (int j = 0; j < 8; ++j) {
            const int d = dg * 8 + j;             // d&7 == j
            uint4 w;
            w.x = pack_bf16(va[0][j], va[1][j]);
            w.y = pack_bf16(va[2][j], va[3][j]);
            w.z = pack_bf16(va[4][j], va[5][j]);
            w.w = pack_bf16(va[6][j], va[7][j]);
            *reinterpret_cast<uint4*>(db + d * D_DIM + 8 * (kg8 ^ j)) = w;
        }
    }
}

// ---------------------------------------------------------------------------
// Main: flash fwd, S^T formulation, bf16 K/V from workspace.
// LDS = 2*8K (K dbuf) + 2*8K (V dbuf) + 8K (P) = 40960 B -> 4 blocks/CU.
// ---------------------------------------------------------------------------
__global__ __launch_bounds__(256, 4)
void fa_fwd(const float* __restrict__ qg,
            const unsigned short* __restrict__ kb,
            const unsigned short* __restrict__ vb,
            float* __restrict__ og)
{
    const int head = blockIdx.x;          // fast dim -> XCD spread
    const int pr   = blockIdx.y;          // 0..15: q-tiles {pr, 31-pr}
    const int tid  = threadIdx.x;
    const int wave = tid >> 6;
    const int lane = tid & 63;
    const int m16  = lane & 15;
    const int quad = lane >> 4;

    __shared__ unsigned short Kl[2][TK * D_DIM];   // swizzled [kv][d] bf16
    __shared__ unsigned short Vt[2][TK * D_DIM];   // swizzled [d][kv] bf16
    __shared__ unsigned short Pl[4][16 * TK];      // per-wave swizzled [q][kv]

    const size_t hoff = (size_t)head * S_LEN * D_DIM;
    const unsigned short* kbh = kb + hoff;
    const unsigned short* vbh = vb + hoff;
    float* __restrict__ ogh = og + hoff;

    // swizzled byte columns within a 128B row (row&7 == m16&7 for all rows used)
    const int swz  = (m16 & 7) << 4;
    const int colA = (quad * 16) ^ swz;
    const int colB = (64 + quad * 16) ^ swz;
    const int rowB = m16 * 128;
    const int sgo  = wave * 512 + lane * 8;   // staging src offset (shorts)

    char* klds = (char*)&Kl[0][0];
    char* vlds = (char*)&Vt[0][0];
    char* plds = (char*)&Pl[0][0] + wave * 2048 + m16 * 128;
    char* kw   = klds + wave * 1024;          // wave-uniform stage dest (buf 0)
    char* vw   = vlds + wave * 1024;

    const float QSC = 0.18033688011112042f;   // 1/8 * log2(e): scores in log2 domain

    for (int pass = 0; pass < 2; ++pass) {
        const int q0 = ((pass == 0) ? pr : (31 - pr)) * TK;
        const int T  = q0 >> 6;               // last (diagonal) tile index

        // ---- Q fragment (B operand): n=q=m16, k=d=quad*8+j; scaled 1/8*log2e
        bf16x8 qf[2];
        {
            const float* qp = qg + hoff + (size_t)(q0 + wave * 16 + m16) * D_DIM + quad * 8;
            #pragma unroll
            for (int c = 0; c < 2; ++c) {
                float4 a = reinterpret_cast<const float4*>(qp + c * 32)[0];
                float4 b = reinterpret_cast<const float4*>(qp + c * 32)[1];
                unsigned int u0 = pack_bf16(a.x * QSC, a.y * QSC);
                unsigned int u1 = pack_bf16(a.z * QSC, a.w * QSC);
                unsigned int u2 = pack_bf16(b.x * QSC, b.y * QSC);
                unsigned int u3 = pack_bf16(b.z * QSC, b.w * QSC);
                qf[c][0] = (short)(u0 & 0xFFFF); qf[c][1] = (short)(u0 >> 16);
                qf[c][2] = (short)(u1 & 0xFFFF); qf[c][3] = (short)(u1 >> 16);
                qf[c][4] = (short)(u2 & 0xFFFF); qf[c][5] = (short)(u2 >> 16);
                qf[c][6] = (short)(u3 & 0xFFFF); qf[c][7] = (short)(u3 >> 16);
            }
        }

        float l_i = 0.f;
        // mc = -m_i broadcast into the QK C-operand: sv emerges already
        // relative to the running max. m_i is tracked only through mc.
        f32x4 mc = (f32x4){MINIT, MINIT, MINIT, MINIT};
        f32x4 oacc[4];
        #pragma unroll
        for (int nc = 0; nc < 4; ++nc) oacc[nc] = (f32x4){0.f, 0.f, 0.f, 0.f};

        // ---- prologue: stage tile 0 into buf 0 (4x global_load_lds / wave)
        {
            const unsigned short* ks = kbh + sgo;
            const unsigned short* vs = vbh + sgo;
            stage16(ks,        kw);
            stage16(ks + 2048, kw + 4096);
            stage16(vs,        vw);
            stage16(vs + 2048, vw + 4096);
        }
        __syncthreads();   // compiler drains vmcnt(0) before s_barrier

        int cur = 0;
        for (int t = 0; t <= T; ++t) {
            // ---- issue next-tile stage first: HBM/L2 latency hides under compute
            if (t < T) {
                const unsigned short* ks = kbh + (size_t)(t + 1) * 4096 + sgo;
                const unsigned short* vs = vbh + (size_t)(t + 1) * 4096 + sgo;
                const int nb = (cur ^ 1) * 8192;
                stage16(ks,        kw + nb);
                stage16(ks + 2048, kw + nb + 4096);
                stage16(vs,        vw + nb);
                stage16(vs + 2048, vw + nb + 4096);
            }

            const char* kt = klds + cur * 8192;
            const char* vt = vlds + cur * 8192;

            // ---- S^T = K·Q^T + (-m_i)  (C: row=kv=nt*16+quad*4+r, col=q=m16)
            float sv[4][4];
            __builtin_amdgcn_s_setprio(1);
            #pragma unroll
            for (int nt = 0; nt < 4; ++nt) {
                const char* kr = kt + nt * 2048 + rowB;
                bf16x8 kf0 = *reinterpret_cast<const bf16x8*>(kr + colA);
                bf16x8 kf1 = *reinterpret_cast<const bf16x8*>(kr + colB);
                f32x4 acc = __builtin_amdgcn_mfma_f32_16x16x32_bf16(kf0, qf[0], mc, 0, 0, 0);
                acc = __builtin_amdgcn_mfma_f32_16x16x32_bf16(kf1, qf[1], acc, 0, 0, 0);
                #pragma unroll
                for (int r = 0; r < 4; ++r) sv[nt][r] = acc[r];
            }
            __builtin_amdgcn_s_setprio(0);

            // ---- causal mask (diagonal tile only); MASKV dominates any mc shift
            if (t == T) {
                #pragma unroll
                for (int nt = 0; nt < 4; ++nt)
                    #pragma unroll
                    for (int r = 0; r < 4; ++r)
                        if (nt * 16 + quad * 4 + r > wave * 16 + m16) sv[nt][r] = MASKV;
            }

            // ---- row max (relative): v_max3 tree, then quad reduce
            float t0 = fmax3(sv[0][0], sv[0][1], sv[0][2]);
            float t1 = fmax3(sv[0][3], sv[1][0], sv[1][1]);
            float t2 = fmax3(sv[1][2], sv[1][3], sv[2][0]);
            float t3 = fmax3(sv[2][1], sv[2][2], sv[2][3]);
            float t4 = fmax3(sv[3][0], sv[3][1], sv[3][2]);
            float u0 = fmax3(t0, t1, t2);
            float u1 = fmax3(t3, t4, sv[3][3]);
            float rm = fmaxf(u0, u1);
            rm = fmaxf(rm, __shfl_xor(rm, 16, 64));
            rm = fmaxf(rm, __shfl_xor(rm, 32, 64));

            // ---- defer-max (T13), relative domain. Tile 0 always triggers
            // (sv ~ +MINIT). Subs happen only on rescale tiles.
            if (__any(rm > DEFER_THR)) {
                float mx    = fmaxf(rm, 0.f);        // per-lane max shift
                float alpha = fast_exp2(-mx);
                l_i *= alpha;
                #pragma unroll
                for (int nc = 0; nc < 4; ++nc)
                    #pragma unroll
                    for (int r = 0; r < 4; ++r) oacc[nc][r] *= alpha;
                #pragma unroll
                for (int nt = 0; nt < 4; ++nt)
                    #pragma unroll
                    for (int r = 0; r < 4; ++r) sv[nt][r] -= mx;
                #pragma unroll
                for (int r = 0; r < 4; ++r) mc[r] -= mx;
            }

            float rs = 0.f;
            #pragma unroll
            for (int nt = 0; nt < 4; ++nt) {
                float e0 = fast_exp2(sv[nt][0]);     // bounded by 2^DEFER_THR
                float e1 = fast_exp2(sv[nt][1]);
                float e2 = fast_exp2(sv[nt][2]);
                float e3 = fast_exp2(sv[nt][3]);
                rs += (e0 + e1) + (e2 + e3);
                uint2 pw;
                pw.x = pack_bf16_fast(e0, e1);
                pw.y = pack_bf16_fast(e2, e3);
                *reinterpret_cast<uint2*>(plds + ((nt * 32 + quad * 8) ^ swz)) = pw;
            }
            rs += __shfl_xor(rs, 16, 64);
            rs += __shfl_xor(rs, 32, 64);
            l_i += rs;

            // Pl is wave-private: intra-wave DS ordering only (keeps staging
            // loads in flight — no barrier here). Same pattern as passing R6/R8/R9.
            asm volatile("s_waitcnt lgkmcnt(0)" ::: "memory");

            // ---- O^T += V^T·P^T  (C: row=d, col=q)
            bf16x8 pf0 = *reinterpret_cast<const bf16x8*>(plds + colA);
            bf16x8 pf1 = *reinterpret_cast<const bf16x8*>(plds + colB);
            __builtin_amdgcn_s_setprio(1);
            #pragma unroll
            for (int nc = 0; nc < 4; ++nc) {
                const char* vr = vt + nc * 2048 + rowB;
                bf16x8 vf0 = *reinterpret_cast<const bf16x8*>(vr + colA);
                bf16x8 vf1 = *reinterpret_cast<const bf16x8*>(vr + colB);
                oacc[nc] = __builtin_amdgcn_mfma_f32_16x16x32_bf16(vf0, pf0, oacc[nc], 0, 0, 0);
                oacc[nc] = __builtin_amdgcn_mfma_f32_16x16x32_bf16(vf1, pf1, oacc[nc], 0, 0, 0);
            }
            __builtin_amdgcn_s_setprio(0);

            __syncthreads();   // drains vmcnt (next tile staged) + lgkmcnt
            cur ^= 1;
        }

        // ---- epilogue: lane owns q=q0+wave*16+m16; O^T rows d -> float4 stores
        float inv = 1.0f / l_i;
        float* op = ogh + (size_t)(q0 + wave * 16 + m16) * D_DIM;
        #pragma unroll
        for (int nc = 0; nc < 4; ++nc) {
            float4 o4;
            o4.x = oacc[nc][0] * inv;
            o4.y = oacc[nc][1] * inv;
            o4.z = oacc[nc][2] * inv;
            o4.w = oacc[nc][3] * inv;
            reinterpret_cast<float4*>(op + nc * 16 + quad * 4)[0] = o4;
        }
    }
}

// ---------------------------------------------------------------------------
// Fallback (R6 kernel, verbatim) — used only if ws_size < 32 MiB.
// ---------------------------------------------------------------------------
__global__ __launch_bounds__(256, 4)
void fa_fwd_fb(const float* __restrict__ qg,
               const float* __restrict__ kg,
               const float* __restrict__ vg,
               float* __restrict__ og)
{
    const int head = blockIdx.x;
    const int pr   = blockIdx.y;
    const int tid  = threadIdx.x;
    const int wave = tid >> 6;
    const int lane = tid & 63;
    const int m16  = lane & 15;
    const int quad = lane >> 4;

    __shared__ unsigned short Kl[TK][LSTR];
    __shared__ unsigned short Vt[D_DIM][LSTR];
    __shared__ unsigned short Pl[4][16][LSTR];

    const size_t hoff = (size_t)head * S_LEN * D_DIM;
    const float* kh = kg + hoff;
    const float* vh = vg + hoff;

    const int ksr = tid >> 2;
    const int ksc = (tid & 3) << 4;
    const int va  = lane >> 3;
    const int vb  = lane & 7;
    const int vrr = wave * 16 + 2 * vb;
    const int vcc = 8 * va;
    const float LOG2E = 1.4426950408889634f;

    for (int pass = 0; pass < 2; ++pass) {
        const int q0 = ((pass == 0) ? pr : (31 - pr)) * TK;

        bf16x8 qf[2];
        {
            const float* qp = qg + hoff + (size_t)(q0 + wave * 16 + m16) * D_DIM + quad * 8;
            #pragma unroll
            for (int c = 0; c < 2; ++c) {
                float4 a = reinterpret_cast<const float4*>(qp + c * 32)[0];
                float4 b = reinterpret_cast<const float4*>(qp + c * 32)[1];
                unsigned int u0 = pack_bf16(a.x * 0.125f, a.y * 0.125f);
                unsigned int u1 = pack_bf16(a.z * 0.125f, a.w * 0.125f);
                unsigned int u2 = pack_bf16(b.x * 0.125f, b.y * 0.125f);
                unsigned int u3 = pack_bf16(b.z * 0.125f, b.w * 0.125f);
                qf[c][0] = (short)(u0 & 0xFFFF); qf[c][1] = (short)(u0 >> 16);
                qf[c][2] = (short)(u1 & 0xFFFF); qf[c][3] = (short)(u1 >> 16);
                qf[c][4] = (short)(u2 & 0xFFFF); qf[c][5] = (short)(u2 >> 16);
                qf[c][6] = (short)(u3 & 0xFFFF); qf[c][7] = (short)(u3 >> 16);
            }
        }

        float m_i = MNEG, l_i = 0.f;
        f32x4 oacc[4];
        #pragma unroll
        for (int nc = 0; nc < 4; ++nc) oacc[nc] = (f32x4){0.f, 0.f, 0.f, 0.f};

        float4 kA, kB, kC, kD, vA, vB, vC, vD;
        {
            const float* kp = kh + (size_t)ksr * D_DIM + ksc;
            kA = reinterpret_cast<const float4*>(kp)[0];
            kB = reinterpret_cast<const float4*>(kp)[1];
            kC = reinterpret_cast<const float4*>(kp)[2];
            kD = reinterpret_cast<const float4*>(kp)[3];
            const float* vp = vh + (size_t)vrr * D_DIM + vcc;
            vA = reinterpret_cast<const float4*>(vp)[0];
            vB = reinterpret_cast<const float4*>(vp)[1];
            vC = reinterpret_cast<const float4*>(vp + D_DIM)[0];
            vD = reinterpret_cast<const float4*>(vp + D_DIM)[1];
        }

        for (int j0 = 0; j0 <= q0; j0 += TK) {
            __syncthreads();
            {
                uint4 w0, w1;
                w0.x = pack_bf16(kA.x, kA.y); w0.y = pack_bf16(kA.z, kA.w);
                w0.z = pack_bf16(kB.x, kB.y); w0.w = pack_bf16(kB.z, kB.w);
                w1.x = pack_bf16(kC.x, kC.y); w1.y = pack_bf16(kC.z, kC.w);
                w1.z = pack_bf16(kD.x, kD.y); w1.w = pack_bf16(kD.z, kD.w);
                *reinterpret_cast<uint4*>(&Kl[ksr][ksc])     = w0;
                *reinterpret_cast<uint4*>(&Kl[ksr][ksc + 8]) = w1;

                float r0[8] = {vA.x, vA.y, vA.z, vA.w, vB.x, vB.y, vB.z, vB.w};
                float r1[8] = {vC.x, vC.y, vC.z, vC.w, vD.x, vD.y, vD.z, vD.w};
                #pragma unroll
                for (int jj = 0; jj < 8; ++jj) {
                    int j = (jj + va) & 7;
                    *reinterpret_cast<unsigned int*>(&Vt[vcc + j][vrr]) = pack_bf16(r0[j], r1[j]);
                }
            }
            __syncthreads();

            if (j0 + TK <= q0) {
                const float* kp = kh + (size_t)(j0 + TK + ksr) * D_DIM + ksc;
                kA = reinterpret_cast<const float4*>(kp)[0];
                kB = reinterpret_cast<const float4*>(kp)[1];
                kC = reinterpret_cast<const float4*>(kp)[2];
                kD = reinterpret_cast<const float4*>(kp)[3];
                const float* vp = vh + (size_t)(j0 + TK + vrr) * D_DIM + vcc;
                vA = reinterpret_cast<const float4*>(vp)[0];
                vB = reinterpret_cast<const float4*>(vp)[1];
                vC = reinterpret_cast<const float4*>(vp + D_DIM)[0];
                vD = reinterpret_cast<const float4*>(vp + D_DIM)[1];
            }

            float sv[4][4];
            #pragma unroll
            for (int nt = 0; nt < 4; ++nt) {
                f32x4 acc = (f32x4){0.f, 0.f, 0.f, 0.f};
                bf16x8 kf0 = *reinterpret_cast<const bf16x8*>(&Kl[nt * 16 + m16][quad * 8]);
                bf16x8 kf1 = *reinterpret_cast<const bf16x8*>(&Kl[nt * 16 + m16][32 + quad * 8]);
                acc = __builtin_amdgcn_mfma_f32_16x16x32_bf16(kf0, qf[0], acc, 0, 0, 0);
                acc = __builtin_amdgcn_mfma_f32_16x16x32_bf16(kf1, qf[1], acc, 0, 0, 0);
                #pragma unroll
                for (int r = 0; r < 4; ++r) sv[nt][r] = acc[r];
            }

            if (j0 == q0) {
                #pragma unroll
                for (int nt = 0; nt < 4; ++nt)
                    #pragma unroll
                    for (int r = 0; r < 4; ++r)
                        if (nt * 16 + quad * 4 + r > wave * 16 + m16) sv[nt][r] = MNEG;
            }

            float a0 = fmaxf(fmaxf(sv[0][0], sv[0][1]), fmaxf(sv[0][2], sv[0][3]));
            float a1 = fmaxf(fmaxf(sv[1][0], sv[1][1]), fmaxf(sv[1][2], sv[1][3]));
            float a2 = fmaxf(fmaxf(sv[2][0], sv[2][1]), fmaxf(sv[2][2], sv[2][3]));
            float a3 = fmaxf(fmaxf(sv[3][0], sv[3][1]), fmaxf(sv[3][2], sv[3][3]));
            float rm = fmaxf(fmaxf(a0, a1), fmaxf(a2, a3));
            rm = fmaxf(rm, __shfl_xor(rm, 16, 64));
            rm = fmaxf(rm, __shfl_xor(rm, 32, 64));
            float mnew  = fmaxf(m_i, rm);
            float alpha = fast_exp2((m_i - mnew) * LOG2E);
            float msc   = mnew * LOG2E;
            m_i = mnew;

            float rs = 0.f;
            #pragma unroll
            for (int nt = 0; nt < 4; ++nt) {
                float e0 = fast_exp2(fmaf(sv[nt][0], LOG2E, -msc));
                float e1 = fast_exp2(fmaf(sv[nt][1], LOG2E, -msc));
                float e2 = fast_exp2(fmaf(sv[nt][2], LOG2E, -msc));
                float e3 = fast_exp2(fmaf(sv[nt][3], LOG2E, -msc));
                rs += (e0 + e1) + (e2 + e3);
                uint2 pw;
                pw.x = pack_bf16(e0, e1);
                pw.y = pack_bf16(e2, e3);
                *reinterpret_cast<uint2*>(&Pl[wave][m16][nt * 16 + quad * 4]) = pw;
            }
            rs += __shfl_xor(rs, 16, 64);
            rs += __shfl_xor(rs, 32, 64);
            l_i = fmaf(alpha, l_i, rs);

            #pragma unroll
            for (int nc = 0; nc < 4; ++nc)
                #pragma unroll
                for (int r = 0; r < 4; ++r)
                    oacc[nc][r] *= alpha;

            asm volatile("s_waitcnt lgkmcnt(0)" ::: "memory");

            bf16x8 pf0 = *reinterpret_cast<const bf16x8*>(&Pl[wave][m16][quad * 8]);
            bf16x8 pf1 = *reinterpret_cast<const bf16x8*>(&Pl[wave][m16][32 + quad * 8]);
            #pragma unroll
            for (int nc = 0; nc < 4; ++nc) {
                bf16x8 vf0 = *reinterpret_cast<const bf16x8*>(&Vt[nc * 16 + m16][quad * 8]);
                bf16x8 vf1 = *reinterpret_cast<const bf16x8*>(&Vt[nc * 16 + m16][32 + quad * 8]);
                oacc[nc] = __builtin_amdgcn_mfma_f32_16x16x32_bf16(vf0, pf0, oacc[nc], 0, 0, 0);
                oacc[nc] = __builtin_amdgcn_mfma_f32_16x16x32_bf16(vf1, pf1, oacc[nc], 0, 0, 0);
            }
        }

        float inv = 1.0f / l_i;
        float* op = og + hoff + (size_t)(q0 + wave * 16 + m16) * D_DIM;
        #pragma unroll
        for (int nc = 0; nc < 4; ++nc) {
            float4 o4;
            o4.x = oacc[nc][0] * inv;
            o4.y = oacc[nc][1] * inv;
            o4.z = oacc[nc][2] * inv;
            o4.w = oacc[nc][3] * inv;
            reinterpret_cast<float4*>(op + nc * 16 + quad * 4)[0] = o4;
        }
    }
}

extern "C" void kernel_launch(void* const* d_in, const int* in_sizes, int n_in,
                              void* d_out, int out_size, void* d_ws, size_t ws_size,
                              hipStream_t stream) {
    const float* q = (const float*)d_in[0];
    const float* k = (const float*)d_in[1];
    const float* v = (const float*)d_in[2];
    float* o = (float*)d_out;
    const size_t kvShorts = (size_t)NHEAD * S_LEN * D_DIM;           // 8.39M
    const size_t wsNeed   = 2 * kvShorts * sizeof(unsigned short);   // 32 MiB
    dim3 grid(NHEAD, 16);
    if (d_ws != nullptr && ws_size >= wsNeed) {
        unsigned short* kb = (unsigned short*)d_ws;
        unsigned short* vb = kb + kvShorts;
        fa_prep<<<PREP_KBLK + 512, 256, 0, stream>>>(k, v, kb, vb);
        fa_fwd<<<grid, 256, 0, stream>>>(q, kb, vb, o);
    } else {
        fa_fwd_fb<<<grid, 256, 0, stream>>>(q, k, v, o);
    }
}

// Round 5
// 200.886 us; speedup vs baseline: 1.1232x; 1.0006x over previous
//
#include <hip/hip_runtime.h>
#include <math.h>

// B=4, H=16, S=2048, D=64 causal attention. fp32 in, fp32 out.
// R11: LDS-pipe fix. K/V MFMA fragments are wave-invariant -> 4 waves/block
// read identical LDS bytes (4x redundancy, ~69% LDS-pipe util at R10).
// Each wave now owns 32 q (two 16-col groups A/B); every K/V fragment read
// feeds 4 MFMAs instead of 2. Q-tile 128, grid 64x8=512 blocks (2/CU, 48KB).
// Causal: group g diagonal at step T-1+g; mask condition there is the same
// `nt*16+quad*4+r > wave*16+m16`; group A fully masked at t==T (shift form).
// Carried: fa_prep O(S) bf16 conversion, global_load_lds staging, dbuf,
// T2 swizzle, log2-domain scores (QSC), relative defer-max (mc in MFMA C),
// v_perm pack, v_max3 tree, s_setprio.
// Fallback to R6 kernel if ws_size < 32 MiB.

#define S_LEN 2048
#define D_DIM 64
#define TK 64
#define NHEAD 64
#define MASKV -30000.0f   // causal mask value (always underflows exp2)
#define MINIT 1000.0f     // initial -m_i: sv(tile0) ~ +1000 -> forces rescale
#define DEFER_THR 12.0f   // log2 domain: P bounded by 2^12
#define MNEG -30000.0f    // fallback kernel only
#define LSTR 72           // fallback kernel only
#define PREP_KBLK 4096

typedef __attribute__((ext_vector_type(8))) short bf16x8;
typedef __attribute__((ext_vector_type(4))) float f32x4;

static __device__ __forceinline__ float fast_exp2(float x) {
#if __has_builtin(__builtin_amdgcn_exp2f)
    return __builtin_amdgcn_exp2f(x);   // v_exp_f32: 2^x, large-negative -> 0
#else
    float r;
    asm volatile("v_exp_f32 %0, %1\n\ts_nop 1" : "=v"(r) : "v"(x));
    return r;
#endif
}

// clang fuses nested fmaxf to v_max3_f32 (exact)
static __device__ __forceinline__ float fmax3(float a, float b, float c) {
    return fmaxf(fmaxf(a, b), c);
}

// round-half-up fp32->bf16 pair, packed into one dword (a=low, b=high)
static __device__ __forceinline__ unsigned int pack_bf16(float a, float b) {
    union { float f; unsigned int u; } ca, cb;
    ca.f = a; cb.f = b;
    unsigned int ua = ca.u + 0x8000u;
    unsigned int ub = cb.u + 0x8000u;
    return (ua >> 16) | (ub & 0xFFFF0000u);
}

// same bits as pack_bf16, 3 VALU ops: 2 adds + v_perm_b32 byte select.
static __device__ __forceinline__ unsigned int pack_bf16_fast(float a, float b) {
#if __has_builtin(__builtin_amdgcn_perm)
    union { float f; unsigned int u; } ca, cb;
    ca.f = a; cb.f = b;
    return __builtin_amdgcn_perm(cb.u + 0x8000u, ca.u + 0x8000u, 0x07060302u);
#else
    return pack_bf16(a, b);
#endif
}

typedef const __attribute__((address_space(1))) unsigned int* gas1_t;
typedef __attribute__((address_space(3))) unsigned int* las3_t;
// async global->LDS, 16B per lane. LDS dest is wave-uniform base (+lane*16 in HW).
static __device__ __forceinline__ void stage16(const void* g, void* l) {
    __builtin_amdgcn_global_load_lds((gas1_t)g, (las3_t)l, 16, 0, 0);
}

// ---------------------------------------------------------------------------
// Prep: K -> kb (bf16, row-chunk-swizzled), V -> vb (bf16, transposed,
// tile-major, row-chunk-swizzled). Blocks [0,PREP_KBLK): K. Rest: V.
// ---------------------------------------------------------------------------
__global__ __launch_bounds__(256)
void fa_prep(const float* __restrict__ kg, const float* __restrict__ vg,
             unsigned short* __restrict__ kb, unsigned short* __restrict__ vb)
{
    const int tid = threadIdx.x;
    const int bid = blockIdx.x;
    if (bid < PREP_KBLK) {
        // one 16B chunk (8 d-elems) of one K row per thread
        const int cid = bid * 256 + tid;          // (head*S + kv)*8 + ch
        const int ch  = cid & 7;
        const int row = cid >> 3;                 // head*S + kv
        const int kv  = row & (S_LEN - 1);
        const float4* s = reinterpret_cast<const float4*>(kg + (size_t)row * D_DIM + ch * 8);
        float4 a = s[0], b = s[1];
        uint4 w;
        w.x = pack_bf16(a.x, a.y); w.y = pack_bf16(a.z, a.w);
        w.z = pack_bf16(b.x, b.y); w.w = pack_bf16(b.z, b.w);
        const int dst = ch ^ (kv & 7);            // T2 swizzle
        *reinterpret_cast<uint4*>(kb + (size_t)row * D_DIM + dst * 8) = w;
    } else {
        // one 64x64 V tile per wave; lane = (kv-group kg8, d-group dg)
        const int wv   = (bid - PREP_KBLK) * 4 + (tid >> 6);  // head*32 + t
        const int lane = tid & 63;
        const int kg8  = lane >> 3;
        const int dg   = lane & 7;
        const float* s = vg + ((size_t)wv * TK + kg8 * 8) * D_DIM + dg * 8;
        float va[8][8];                            // [kv in group][d in group]
        #pragma unroll
        for (int i = 0; i < 8; ++i) {
            const float4* sp = reinterpret_cast<const float4*>(s + (size_t)i * D_DIM);
            float4 x = sp[0], y = sp[1];
            va[i][0] = x.x; va[i][1] = x.y; va[i][2] = x.z; va[i][3] = x.w;
            va[i][4] = y.x; va[i][5] = y.y; va[i][6] = y.z; va[i][7] = y.w;
        }
        unsigned short* db = vb + (size_t)wv * (TK * D_DIM);  // tile base (8 KB)
        #pragma unroll
        for (int j = 0; j < 8; ++j) {
            const int d = dg * 8 + j;             // d&7 == j
            uint4 w;
            w.x = pack_bf16(va[0][j], va[1][j]);
            w.y = pack_bf16(va[2][j], va[3][j]);
            w.z = pack_bf16(va[4][j], va[5][j]);
            w.w = pack_bf16(va[6][j], va[7][j]);
            *reinterpret_cast<uint4*>(db + d * D_DIM + 8 * (kg8 ^ j)) = w;
        }
    }
}

// online-softmax for one 16-q group (relative domain, defer-max).
// SV: float[4][4]; MC/LI: running state; PL: this group's P base in LDS.
#define SOFTMAX_GROUP(SV, MC, LI, PL)                                          \
    {                                                                          \
        float x0 = fmax3(SV[0][0], SV[0][1], SV[0][2]);                        \
        float x1 = fmax3(SV[0][3], SV[1][0], SV[1][1]);                        \
        float x2 = fmax3(SV[1][2], SV[1][3], SV[2][0]);                        \
        float x3 = fmax3(SV[2][1], SV[2][2], SV[2][3]);                        \
        float x4 = fmax3(SV[3][0], SV[3][1], SV[3][2]);                        \
        float y0 = fmax3(x0, x1, x2);                                          \
        float y1 = fmax3(x3, x4, SV[3][3]);                                    \
        float rm = fmaxf(y0, y1);                                              \
        rm = fmaxf(rm, __shfl_xor(rm, 16, 64));                                \
        rm = fmaxf(rm, __shfl_xor(rm, 32, 64));                                \
        if (__any(rm > DEFER_THR)) {                                           \
            float mx    = fmaxf(rm, 0.f);                                      \
            float alpha = fast_exp2(-mx);                                      \
            LI *= alpha;                                                       \
            _Pragma("unroll")                                                  \
            for (int nc = 0; nc < 4; ++nc)                                     \
                _Pragma("unroll")                                              \
                for (int r = 0; r < 4; ++r) oacc##SV[nc][r] *= alpha;          \
            _Pragma("unroll")                                                  \
            for (int nt = 0; nt < 4; ++nt)                                     \
                _Pragma("unroll")                                              \
                for (int r = 0; r < 4; ++r) SV[nt][r] -= mx;                   \
            _Pragma("unroll")                                                  \
            for (int r = 0; r < 4; ++r) MC[r] -= mx;                           \
        }                                                                      \
        float rs = 0.f;                                                        \
        _Pragma("unroll")                                                      \
        for (int nt = 0; nt < 4; ++nt) {                                       \
            float e0 = fast_exp2(SV[nt][0]);                                   \
            float e1 = fast_exp2(SV[nt][1]);                                   \
            float e2 = fast_exp2(SV[nt][2]);                                   \
            float e3 = fast_exp2(SV[nt][3]);                                   \
            rs += (e0 + e1) + (e2 + e3);                                       \
            uint2 pw;                                                          \
            pw.x = pack_bf16_fast(e0, e1);                                     \
            pw.y = pack_bf16_fast(e2, e3);                                     \
            *reinterpret_cast<uint2*>(PL + ((nt * 32 + quad * 8) ^ swz)) = pw; \
        }                                                                      \
        rs += __shfl_xor(rs, 16, 64);                                          \
        rs += __shfl_xor(rs, 32, 64);                                          \
        LI += rs;                                                              \
    }

// ---------------------------------------------------------------------------
// Main: flash fwd, S^T formulation, bf16 K/V from workspace.
// Q-tile 128 (wave owns 32 q = 2 groups); K/V fragment reads feed 4 MFMAs.
// LDS = 2*8K (K) + 2*8K (V) + 16K (P) = 48K -> 2 blocks/CU (grid-limited).
// ---------------------------------------------------------------------------
__global__ __launch_bounds__(256, 2)
void fa_fwd(const float* __restrict__ qg,
            const unsigned short* __restrict__ kb,
            const unsigned short* __restrict__ vb,
            float* __restrict__ og)
{
    const int head = blockIdx.x;          // fast dim -> XCD spread
    const int pr   = blockIdx.y;          // 0..7: q-tile pairs {pr, 15-pr}
    const int tid  = threadIdx.x;
    const int wave = tid >> 6;
    const int lane = tid & 63;
    const int m16  = lane & 15;
    const int quad = lane >> 4;

    __shared__ unsigned short Kl[2][TK * D_DIM];     // swizzled [kv][d] bf16
    __shared__ unsigned short Vt[2][TK * D_DIM];     // swizzled [d][kv] bf16
    __shared__ unsigned short Pl[4][2][16 * TK];     // per-wave, per-group P

    const size_t hoff = (size_t)head * S_LEN * D_DIM;
    const unsigned short* kbh = kb + hoff;
    const unsigned short* vbh = vb + hoff;
    float* __restrict__ ogh = og + hoff;

    // swizzled byte columns within a 128B row (row&7 == m16&7 for all rows used)
    const int swz  = (m16 & 7) << 4;
    const int colA = (quad * 16) ^ swz;
    const int colB = (64 + quad * 16) ^ swz;
    const int rowB = m16 * 128;
    const int sgo  = wave * 512 + lane * 8;   // staging src offset (shorts)

    char* klds = (char*)&Kl[0][0];
    char* vlds = (char*)&Vt[0][0];
    char* plA  = (char*)&Pl[0][0][0] + wave * 4096 + m16 * 128;
    char* plB  = plA + 2048;
    char* kw   = klds + wave * 1024;          // wave-uniform stage dest (buf 0)
    char* vw   = vlds + wave * 1024;

    const float QSC = 0.18033688011112042f;   // 1/8 * log2(e): log2-domain scores

    for (int pass = 0; pass < 2; ++pass) {
        const int idx = (pass == 0) ? pr : (15 - pr);
        const int q0  = idx * 128;
        const int T   = (q0 >> 6) + 1;        // last kv-tile index (steps 0..T)

        // ---- Q fragments (B operand): group A rows q0+wave*16+m16,
        //      group B rows +64; k=d=quad*8+j; scaled 1/8*log2e
        bf16x8 qfA[2], qfB[2];
        {
            const float* qpA = qg + hoff + (size_t)(q0 + wave * 16 + m16) * D_DIM + quad * 8;
            #pragma unroll
            for (int c = 0; c < 2; ++c) {
                float4 a = reinterpret_cast<const float4*>(qpA + c * 32)[0];
                float4 b = reinterpret_cast<const float4*>(qpA + c * 32)[1];
                unsigned int u0 = pack_bf16(a.x * QSC, a.y * QSC);
                unsigned int u1 = pack_bf16(a.z * QSC, a.w * QSC);
                unsigned int u2 = pack_bf16(b.x * QSC, b.y * QSC);
                unsigned int u3 = pack_bf16(b.z * QSC, b.w * QSC);
                qfA[c][0] = (short)(u0 & 0xFFFF); qfA[c][1] = (short)(u0 >> 16);
                qfA[c][2] = (short)(u1 & 0xFFFF); qfA[c][3] = (short)(u1 >> 16);
                qfA[c][4] = (short)(u2 & 0xFFFF); qfA[c][5] = (short)(u2 >> 16);
                qfA[c][6] = (short)(u3 & 0xFFFF); qfA[c][7] = (short)(u3 >> 16);
            }
            const float* qpB = qpA + 64 * D_DIM;
            #pragma unroll
            for (int c = 0; c < 2; ++c) {
                float4 a = reinterpret_cast<const float4*>(qpB + c * 32)[0];
                float4 b = reinterpret_cast<const float4*>(qpB + c * 32)[1];
                unsigned int u0 = pack_bf16(a.x * QSC, a.y * QSC);
                unsigned int u1 = pack_bf16(a.z * QSC, a.w * QSC);
                unsigned int u2 = pack_bf16(b.x * QSC, b.y * QSC);
                unsigned int u3 = pack_bf16(b.z * QSC, b.w * QSC);
                qfB[c][0] = (short)(u0 & 0xFFFF); qfB[c][1] = (short)(u0 >> 16);
                qfB[c][2] = (short)(u1 & 0xFFFF); qfB[c][3] = (short)(u1 >> 16);
                qfB[c][4] = (short)(u2 & 0xFFFF); qfB[c][5] = (short)(u2 >> 16);
                qfB[c][6] = (short)(u3 & 0xFFFF); qfB[c][7] = (short)(u3 >> 16);
            }
        }

        float lA = 0.f, lB = 0.f;
        f32x4 mcA = (f32x4){MINIT, MINIT, MINIT, MINIT};
        f32x4 mcB = (f32x4){MINIT, MINIT, MINIT, MINIT};
        f32x4 oaccsvA[4], oaccsvB[4];   // names pair with SOFTMAX_GROUP macro
        #pragma unroll
        for (int nc = 0; nc < 4; ++nc) {
            oaccsvA[nc] = (f32x4){0.f, 0.f, 0.f, 0.f};
            oaccsvB[nc] = (f32x4){0.f, 0.f, 0.f, 0.f};
        }

        // ---- prologue: stage tile 0 into buf 0 (4x global_load_lds / wave)
        {
            const unsigned short* ks = kbh + sgo;
            const unsigned short* vs = vbh + sgo;
            stage16(ks,        kw);
            stage16(ks + 2048, kw + 4096);
            stage16(vs,        vw);
            stage16(vs + 2048, vw + 4096);
        }
        __syncthreads();   // compiler drains vmcnt(0) before s_barrier

        int cur = 0;
        for (int t = 0; t <= T; ++t) {
            // ---- issue next-tile stage first: latency hides under compute
            if (t < T) {
                const unsigned short* ks = kbh + (size_t)(t + 1) * 4096 + sgo;
                const unsigned short* vs = vbh + (size_t)(t + 1) * 4096 + sgo;
                const int nb = (cur ^ 1) * 8192;
                stage16(ks,        kw + nb);
                stage16(ks + 2048, kw + nb + 4096);
                stage16(vs,        vw + nb);
                stage16(vs + 2048, vw + nb + 4096);
            }

            const char* kt = klds + cur * 8192;
            const char* vt = vlds + cur * 8192;

            // ---- S^T = K·Q^T + (-m)  — each K fragment feeds both groups
            float svA[4][4], svB[4][4];
            __builtin_amdgcn_s_setprio(1);
            #pragma unroll
            for (int nt = 0; nt < 4; ++nt) {
                const char* kr = kt + nt * 2048 + rowB;
                bf16x8 kf0 = *reinterpret_cast<const bf16x8*>(kr + colA);
                bf16x8 kf1 = *reinterpret_cast<const bf16x8*>(kr + colB);
                f32x4 aA = __builtin_amdgcn_mfma_f32_16x16x32_bf16(kf0, qfA[0], mcA, 0, 0, 0);
                aA = __builtin_amdgcn_mfma_f32_16x16x32_bf16(kf1, qfA[1], aA, 0, 0, 0);
                f32x4 aB = __builtin_amdgcn_mfma_f32_16x16x32_bf16(kf0, qfB[0], mcB, 0, 0, 0);
                aB = __builtin_amdgcn_mfma_f32_16x16x32_bf16(kf1, qfB[1], aB, 0, 0, 0);
                #pragma unroll
                for (int r = 0; r < 4; ++r) { svA[nt][r] = aA[r]; svB[nt][r] = aB[r]; }
            }
            __builtin_amdgcn_s_setprio(0);

            // ---- causal masks. Group A diagonal at t==T-1, dead at t==T
            // (shift form covers both); group B diagonal at t==T.
            if (t >= T - 1) {
                const int sh = (t - (T - 1)) << 6;
                #pragma unroll
                for (int nt = 0; nt < 4; ++nt)
                    #pragma unroll
                    for (int r = 0; r < 4; ++r)
                        if (sh + nt * 16 + quad * 4 + r > wave * 16 + m16) svA[nt][r] = MASKV;
            }
            if (t == T) {
                #pragma unroll
                for (int nt = 0; nt < 4; ++nt)
                    #pragma unroll
                    for (int r = 0; r < 4; ++r)
                        if (nt * 16 + quad * 4 + r > wave * 16 + m16) svB[nt][r] = MASKV;
            }

            // ---- online softmax per group (relative domain, defer-max)
            SOFTMAX_GROUP(svA, mcA, lA, plA)
            SOFTMAX_GROUP(svB, mcB, lB, plB)

            // Pl is wave-private: intra-wave DS ordering only (keeps staging
            // loads in flight — no barrier here).
            asm volatile("s_waitcnt lgkmcnt(0)" ::: "memory");

            // ---- O^T += V^T·P^T — each V fragment feeds both groups
            bf16x8 pfA0 = *reinterpret_cast<const bf16x8*>(plA + colA);
            bf16x8 pfA1 = *reinterpret_cast<const bf16x8*>(plA + colB);
            bf16x8 pfB0 = *reinterpret_cast<const bf16x8*>(plB + colA);
            bf16x8 pfB1 = *reinterpret_cast<const bf16x8*>(plB + colB);
            __builtin_amdgcn_s_setprio(1);
            #pragma unroll
            for (int nc = 0; nc < 4; ++nc) {
                const char* vr = vt + nc * 2048 + rowB;
                bf16x8 vf0 = *reinterpret_cast<const bf16x8*>(vr + colA);
                bf16x8 vf1 = *reinterpret_cast<const bf16x8*>(vr + colB);
                oaccsvA[nc] = __builtin_amdgcn_mfma_f32_16x16x32_bf16(vf0, pfA0, oaccsvA[nc], 0, 0, 0);
                oaccsvA[nc] = __builtin_amdgcn_mfma_f32_16x16x32_bf16(vf1, pfA1, oaccsvA[nc], 0, 0, 0);
                oaccsvB[nc] = __builtin_amdgcn_mfma_f32_16x16x32_bf16(vf0, pfB0, oaccsvB[nc], 0, 0, 0);
                oaccsvB[nc] = __builtin_amdgcn_mfma_f32_16x16x32_bf16(vf1, pfB1, oaccsvB[nc], 0, 0, 0);
            }
            __builtin_amdgcn_s_setprio(0);

            __syncthreads();   // drains vmcnt (next tile staged) + lgkmcnt
            cur ^= 1;
        }

        // ---- epilogue: group A row q0+wave*16+m16, group B +64
        {
            float inv = 1.0f / lA;
            float* op = ogh + (size_t)(q0 + wave * 16 + m16) * D_DIM;
            #pragma unroll
            for (int nc = 0; nc < 4; ++nc) {
                float4 o4;
                o4.x = oaccsvA[nc][0] * inv;
                o4.y = oaccsvA[nc][1] * inv;
                o4.z = oaccsvA[nc][2] * inv;
                o4.w = oaccsvA[nc][3] * inv;
                reinterpret_cast<float4*>(op + nc * 16 + quad * 4)[0] = o4;
            }
        }
        {
            float inv = 1.0f / lB;
            float* op = ogh + (size_t)(q0 + 64 + wave * 16 + m16) * D_DIM;
            #pragma unroll
            for (int nc = 0; nc < 4; ++nc) {
                float4 o4;
                o4.x = oaccsvB[nc][0] * inv;
                o4.y = oaccsvB[nc][1] * inv;
                o4.z = oaccsvB[nc][2] * inv;
                o4.w = oaccsvB[nc][3] * inv;
                reinterpret_cast<float4*>(op + nc * 16 + quad * 4)[0] = o4;
            }
        }
    }
}

// ---------------------------------------------------------------------------
// Fallback (R6 kernel, verbatim) — used only if ws_size < 32 MiB.
// ---------------------------------------------------------------------------
__global__ __launch_bounds__(256, 4)
void fa_fwd_fb(const float* __restrict__ qg,
               const float* __restrict__ kg,
               const float* __restrict__ vg,
               float* __restrict__ og)
{
    const int head = blockIdx.x;
    const int pr   = blockIdx.y;
    const int tid  = threadIdx.x;
    const int wave = tid >> 6;
    const int lane = tid & 63;
    const int m16  = lane & 15;
    const int quad = lane >> 4;

    __shared__ unsigned short Kl[TK][LSTR];
    __shared__ unsigned short Vt[D_DIM][LSTR];
    __shared__ unsigned short Pl[4][16][LSTR];

    const size_t hoff = (size_t)head * S_LEN * D_DIM;
    const float* kh = kg + hoff;
    const float* vh = vg + hoff;

    const int ksr = tid >> 2;
    const int ksc = (tid & 3) << 4;
    const int va  = lane >> 3;
    const int vb  = lane & 7;
    const int vrr = wave * 16 + 2 * vb;
    const int vcc = 8 * va;
    const float LOG2E = 1.4426950408889634f;

    for (int pass = 0; pass < 2; ++pass) {
        const int q0 = ((pass == 0) ? pr : (31 - pr)) * TK;

        bf16x8 qf[2];
        {
            const float* qp = qg + hoff + (size_t)(q0 + wave * 16 + m16) * D_DIM + quad * 8;
            #pragma unroll
            for (int c = 0; c < 2; ++c) {
                float4 a = reinterpret_cast<const float4*>(qp + c * 32)[0];
                float4 b = reinterpret_cast<const float4*>(qp + c * 32)[1];
                unsigned int u0 = pack_bf16(a.x * 0.125f, a.y * 0.125f);
                unsigned int u1 = pack_bf16(a.z * 0.125f, a.w * 0.125f);
                unsigned int u2 = pack_bf16(b.x * 0.125f, b.y * 0.125f);
                unsigned int u3 = pack_bf16(b.z * 0.125f, b.w * 0.125f);
                qf[c][0] = (short)(u0 & 0xFFFF); qf[c][1] = (short)(u0 >> 16);
                qf[c][2] = (short)(u1 & 0xFFFF); qf[c][3] = (short)(u1 >> 16);
                qf[c][4] = (short)(u2 & 0xFFFF); qf[c][5] = (short)(u2 >> 16);
                qf[c][6] = (short)(u3 & 0xFFFF); qf[c][7] = (short)(u3 >> 16);
            }
        }

        float m_i = MNEG, l_i = 0.f;
        f32x4 oacc[4];
        #pragma unroll
        for (int nc = 0; nc < 4; ++nc) oacc[nc] = (f32x4){0.f, 0.f, 0.f, 0.f};

        float4 kA, kB, kC, kD, vA, vB, vC, vD;
        {
            const float* kp = kh + (size_t)ksr * D_DIM + ksc;
            kA = reinterpret_cast<const float4*>(kp)[0];
            kB = reinterpret_cast<const float4*>(kp)[1];
            kC = reinterpret_cast<const float4*>(kp)[2];
            kD = reinterpret_cast<const float4*>(kp)[3];
            const float* vp = vh + (size_t)vrr * D_DIM + vcc;
            vA = reinterpret_cast<const float4*>(vp)[0];
            vB = reinterpret_cast<const float4*>(vp)[1];
            vC = reinterpret_cast<const float4*>(vp + D_DIM)[0];
            vD = reinterpret_cast<const float4*>(vp + D_DIM)[1];
        }

        for (int j0 = 0; j0 <= q0; j0 += TK) {
            __syncthreads();
            {
                uint4 w0, w1;
                w0.x = pack_bf16(kA.x, kA.y); w0.y = pack_bf16(kA.z, kA.w);
                w0.z = pack_bf16(kB.x, kB.y); w0.w = pack_bf16(kB.z, kB.w);
                w1.x = pack_bf16(kC.x, kC.y); w1.y = pack_bf16(kC.z, kC.w);
                w1.z = pack_bf16(kD.x, kD.y); w1.w = pack_bf16(kD.z, kD.w);
                *reinterpret_cast<uint4*>(&Kl[ksr][ksc])     = w0;
                *reinterpret_cast<uint4*>(&Kl[ksr][ksc + 8]) = w1;

                float r0[8] = {vA.x, vA.y, vA.z, vA.w, vB.x, vB.y, vB.z, vB.w};
                float r1[8] = {vC.x, vC.y, vC.z, vC.w, vD.x, vD.y, vD.z, vD.w};
                #pragma unroll
                for (int jj = 0; jj < 8; ++jj) {
                    int j = (jj + va) & 7;
                    *reinterpret_cast<unsigned int*>(&Vt[vcc + j][vrr]) = pack_bf16(r0[j], r1[j]);
                }
            }
            __syncthreads();

            if (j0 + TK <= q0) {
                const float* kp = kh + (size_t)(j0 + TK + ksr) * D_DIM + ksc;
                kA = reinterpret_cast<const float4*>(kp)[0];
                kB = reinterpret_cast<const float4*>(kp)[1];
                kC = reinterpret_cast<const float4*>(kp)[2];
                kD = reinterpret_cast<const float4*>(kp)[3];
                const float* vp = vh + (size_t)(j0 + TK + vrr) * D_DIM + vcc;
                vA = reinterpret_cast<const float4*>(vp)[0];
                vB = reinterpret_cast<const float4*>(vp)[1];
                vC = reinterpret_cast<const float4*>(vp + D_DIM)[0];
                vD = reinterpret_cast<const float4*>(vp + D_DIM)[1];
            }

            float sv[4][4];
            #pragma unroll
            for (int nt = 0; nt < 4; ++nt) {
                f32x4 acc = (f32x4){0.f, 0.f, 0.f, 0.f};
                bf16x8 kf0 = *reinterpret_cast<const bf16x8*>(&Kl[nt * 16 + m16][quad * 8]);
                bf16x8 kf1 = *reinterpret_cast<const bf16x8*>(&Kl[nt * 16 + m16][32 + quad * 8]);
                acc = __builtin_amdgcn_mfma_f32_16x16x32_bf16(kf0, qf[0], acc, 0, 0, 0);
                acc = __builtin_amdgcn_mfma_f32_16x16x32_bf16(kf1, qf[1], acc, 0, 0, 0);
                #pragma unroll
                for (int r = 0; r < 4; ++r) sv[nt][r] = acc[r];
            }

            if (j0 == q0) {
                #pragma unroll
                for (int nt = 0; nt < 4; ++nt)
                    #pragma unroll
                    for (int r = 0; r < 4; ++r)
                        if (nt * 16 + quad * 4 + r > wave * 16 + m16) sv[nt][r] = MNEG;
            }

            float a0 = fmaxf(fmaxf(sv[0][0], sv[0][1]), fmaxf(sv[0][2], sv[0][3]));
            float a1 = fmaxf(fmaxf(sv[1][0], sv[1][1]), fmaxf(sv[1][2], sv[1][3]));
            float a2 = fmaxf(fmaxf(sv[2][0], sv[2][1]), fmaxf(sv[2][2], sv[2][3]));
            float a3 = fmaxf(fmaxf(sv[3][0], sv[3][1]), fmaxf(sv[3][2], sv[3][3]));
            float rm = fmaxf(fmaxf(a0, a1), fmaxf(a2, a3));
            rm = fmaxf(rm, __shfl_xor(rm, 16, 64));
            rm = fmaxf(rm, __shfl_xor(rm, 32, 64));
            float mnew  = fmaxf(m_i, rm);
            float alpha = fast_exp2((m_i - mnew) * LOG2E);
            float msc   = mnew * LOG2E;
            m_i = mnew;

            float rs = 0.f;
            #pragma unroll
            for (int nt = 0; nt < 4; ++nt) {
                float e0 = fast_exp2(fmaf(sv[nt][0], LOG2E, -msc));
                float e1 = fast_exp2(fmaf(sv[nt][1], LOG2E, -msc));
                float e2 = fast_exp2(fmaf(sv[nt][2], LOG2E, -msc));
                float e3 = fast_exp2(fmaf(sv[nt][3], LOG2E, -msc));
                rs += (e0 + e1) + (e2 + e3);
                uint2 pw;
                pw.x = pack_bf16(e0, e1);
                pw.y = pack_bf16(e2, e3);
                *reinterpret_cast<uint2*>(&Pl[wave][m16][nt * 16 + quad * 4]) = pw;
            }
            rs += __shfl_xor(rs, 16, 64);
            rs += __shfl_xor(rs, 32, 64);
            l_i = fmaf(alpha, l_i, rs);

            #pragma unroll
            for (int nc = 0; nc < 4; ++nc)
                #pragma unroll
                for (int r = 0; r < 4; ++r)
                    oacc[nc][r] *= alpha;

            asm volatile("s_waitcnt lgkmcnt(0)" ::: "memory");

            bf16x8 pf0 = *reinterpret_cast<const bf16x8*>(&Pl[wave][m16][quad * 8]);
            bf16x8 pf1 = *reinterpret_cast<const bf16x8*>(&Pl[wave][m16][32 + quad * 8]);
            #pragma unroll
            for (int nc = 0; nc < 4; ++nc) {
                bf16x8 vf0 = *reinterpret_cast<const bf16x8*>(&Vt[nc * 16 + m16][quad * 8]);
                bf16x8 vf1 = *reinterpret_cast<const bf16x8*>(&Vt[nc * 16 + m16][32 + quad * 8]);
                oacc[nc] = __builtin_amdgcn_mfma_f32_16x16x32_bf16(vf0, pf0, oacc[nc], 0, 0, 0);
                oacc[nc] = __builtin_amdgcn_mfma_f32_16x16x32_bf16(vf1, pf1, oacc[nc], 0, 0, 0);
            }
        }

        float inv = 1.0f / l_i;
        float* op = og + hoff + (size_t)(q0 + wave * 16 + m16) * D_DIM;
        #pragma unroll
        for (int nc = 0; nc < 4; ++nc) {
            float4 o4;
            o4.x = oacc[nc][0] * inv;
            o4.y = oacc[nc][1] * inv;
            o4.z = oacc[nc][2] * inv;
            o4.w = oacc[nc][3] * inv;
            reinterpret_cast<float4*>(op + nc * 16 + quad * 4)[0] = o4;
        }
    }
}

extern "C" void kernel_launch(void* const* d_in, const int* in_sizes, int n_in,
                              void* d_out, int out_size, void* d_ws, size_t ws_size,
                              hipStream_t stream) {
    const float* q = (const float*)d_in[0];
    const float* k = (const float*)d_in[1];
    const float* v = (const float*)d_in[2];
    float* o = (float*)d_out;
    const size_t kvShorts = (size_t)NHEAD * S_LEN * D_DIM;           // 8.39M
    const size_t wsNeed   = 2 * kvShorts * sizeof(unsigned short);   // 32 MiB
    if (d_ws != nullptr && ws_size >= wsNeed) {
        unsigned short* kb = (unsigned short*)d_ws;
        unsigned short* vb = kb + kvShorts;
        fa_prep<<<PREP_KBLK + 512, 256, 0, stream>>>(k, v, kb, vb);
        dim3 grid(NHEAD, 8);
        fa_fwd<<<grid, 256, 0, stream>>>(q, kb, vb, o);
    } else {
        dim3 grid(NHEAD, 16);
        fa_fwd_fb<<<grid, 256, 0, stream>>>(q, k, v, o);
    }
}